// Round 7
// baseline (238.801 us; speedup 1.0000x reference)
//
#include <hip/hip_runtime.h>
#include <hip/hip_bf16.h>

typedef __attribute__((ext_vector_type(8))) short short8;
typedef __attribute__((ext_vector_type(8))) __bf16 bf16x8;
typedef __attribute__((ext_vector_type(4))) float f32x4;

static __device__ __forceinline__ float bflo(unsigned u){ return __uint_as_float(u << 16); }
static __device__ __forceinline__ float bfhi(unsigned u){ return __uint_as_float(u & 0xffff0000u); }
static __device__ __forceinline__ unsigned short f2bf(float f){
  unsigned u = __float_as_uint(f);
  unsigned r = u + 0x7fffu + ((u >> 16) & 1u);
  return (unsigned short)(r >> 16);
}

// ---- fp8 e4m3 conversions ----
#if __has_builtin(__builtin_amdgcn_cvt_pk_fp8_f32)
static __device__ __forceinline__ unsigned char f2e4m3(float f){
  return (unsigned char)(__builtin_amdgcn_cvt_pk_fp8_f32(f, 0.f, 0, false) & 0xff);
}
#else
static __device__ __forceinline__ unsigned char f2e4m3(float f){
  unsigned s = (__float_as_uint(f) >> 31) << 7;
  float a = fabsf(f);
  if (a >= 448.f) return (unsigned char)(s | 0x7e);
  if (a < 0.0009765625f) return (unsigned char)s;
  if (a >= 0.015625f){
    int e; float m = frexpf(a, &e);
    int q = (int)rintf(m * 16.f);
    int E = e - 1 + 7;
    if (q == 16){ q = 8; E++; }
    if (E >= 16) return (unsigned char)(s | 0x7e);
    return (unsigned char)(s | (E << 3) | (q - 8));
  } else {
    int q = (int)rintf(a * 512.f);
    if (q > 7) return (unsigned char)(s | 0x08);
    return (unsigned char)(s | q);
  }
}
#endif

#if __has_builtin(__builtin_amdgcn_cvt_pk_f32_fp8)
static __device__ __forceinline__ float4 e4m3x4_to_f32(unsigned u){
  auto lo = __builtin_amdgcn_cvt_pk_f32_fp8((int)u, false);
  auto hi = __builtin_amdgcn_cvt_pk_f32_fp8((int)u, true);
  return make_float4(lo[0], lo[1], hi[0], hi[1]);
}
#else
static __device__ __forceinline__ float e4m3_1(unsigned b){
  unsigned s = b >> 7, e = (b >> 3) & 15, m = b & 7;
  float v = e ? ldexpf((float)(8 + m) * 0.125f, (int)e - 7) : ldexpf((float)m * 0.125f, -6);
  return s ? -v : v;
}
static __device__ __forceinline__ float4 e4m3x4_to_f32(unsigned u){
  return make_float4(e4m3_1(u & 255), e4m3_1((u >> 8) & 255), e4m3_1((u >> 16) & 255), e4m3_1(u >> 24));
}
#endif

static __device__ __forceinline__ void add16(float* a, uint4 v){
  float4 f0 = e4m3x4_to_f32(v.x), f1 = e4m3x4_to_f32(v.y);
  float4 f2 = e4m3x4_to_f32(v.z), f3 = e4m3x4_to_f32(v.w);
  a[0]+=f0.x; a[1]+=f0.y; a[2]+=f0.z; a[3]+=f0.w;
  a[4]+=f1.x; a[5]+=f1.y; a[6]+=f1.z; a[7]+=f1.w;
  a[8]+=f2.x; a[9]+=f2.y; a[10]+=f2.z; a[11]+=f2.w;
  a[12]+=f3.x; a[13]+=f3.y; a[14]+=f3.z; a[15]+=f3.w;
}

#define NBMAX  1024
#define PART_C 4096
#define STCAP  4096
#define SCAP   5120

// ---------------- bucket pipeline ----------------

__global__ __launch_bounds__(1024) void k_bcnt(const int* __restrict__ dst, int* __restrict__ bcnt,
                                               int E, int NB){
  __shared__ int h[NBMAX];
  const int t = threadIdx.x;
  for (int i = t; i < NB; i += 1024) h[i] = 0;
  __syncthreads();
  for (int e = blockIdx.x * 1024 + t; e < E; e += gridDim.x * 1024)
    atomicAdd(&h[dst[e] >> 7], 1);
  __syncthreads();
  for (int i = t; i < NB; i += 1024) if (h[i]) atomicAdd(&bcnt[i], h[i]);
}

__global__ __launch_bounds__(1024) void k_bscan(const int* __restrict__ bcnt, int* __restrict__ bstart,
    int* __restrict__ bpos, int* __restrict__ rowptr, int NB, int N, int E){
  __shared__ int sc[1024];
  const int t = threadIdx.x;
  int v = (t < NB) ? bcnt[t] : 0;
  sc[t] = v; __syncthreads();
  for (int off = 1; off < 1024; off <<= 1){
    int u = (t >= off) ? sc[t - off] : 0;
    __syncthreads();
    sc[t] += u;
    __syncthreads();
  }
  int excl = sc[t] - v;
  if (t < NB){ bstart[t] = excl; bpos[t] = excl; }
  if (t == 0){ bstart[NB] = E; rowptr[N] = E; }
}

__global__ __launch_bounds__(1024) void k_part(const int* __restrict__ src, const int* __restrict__ dst,
    int* __restrict__ bpos, unsigned* __restrict__ ebuf, int E, int NB)
{
  __shared__ int hist[NBMAX + 1];
  __shared__ int hist2[NBMAX];
  __shared__ int gbase[NBMAX];
  __shared__ int sc[1024];
  __shared__ unsigned staged[PART_C];

  const int t = threadIdx.x;
  const int base = blockIdx.x * PART_C;

  for (int i = t; i < NBMAX; i += 1024){ hist[i] = 0; hist2[i] = 0; }
  __syncthreads();

  unsigned up[4];
  int bb[4];
  #pragma unroll
  for (int j = 0; j < 4; j++){
    int e = base + j * 1024 + t;
    if (e < E){
      int s = src[e], d = dst[e];
      bb[j] = d >> 7;
      up[j] = ((unsigned)s << 7) | (unsigned)(d & 127);
      atomicAdd(&hist[bb[j]], 1);
    } else bb[j] = -1;
  }
  __syncthreads();

  int v = (t < NB) ? hist[t] : 0;
  sc[t] = v; __syncthreads();
  for (int off = 1; off < 1024; off <<= 1){
    int u = (t >= off) ? sc[t - off] : 0;
    __syncthreads();
    sc[t] += u;
    __syncthreads();
  }
  int incl = sc[t];
  if (t < NB) hist[t] = incl - v;
  if (t == NB - 1) hist[NB] = incl;
  if (t < NB && v > 0) gbase[t] = atomicAdd(&bpos[t], v);
  __syncthreads();

  #pragma unroll
  for (int j = 0; j < 4; j++){
    if (bb[j] >= 0){
      int r = atomicAdd(&hist2[bb[j]], 1);
      staged[hist[bb[j]] + r] = up[j];
    }
  }
  __syncthreads();

  int total = hist[NB];
  for (int i = t; i < total; i += 1024){
    int lo = 0, hi = NB;
    while (hi - lo > 1){
      int mid = (lo + hi) >> 1;
      if (hist[mid] <= i) lo = mid; else hi = mid;
    }
    ebuf[gbase[lo] + (i - hist[lo])] = staged[i];
  }
}

__global__ __launch_bounds__(256) void k_bsort(const unsigned* __restrict__ ebuf, const int* __restrict__ bstart,
    int* __restrict__ rowptr, int* __restrict__ colv, float* __restrict__ dinv, int n)
{
  __shared__ int cl[128];
  __shared__ int sc2[256];
  __shared__ unsigned stg[STCAP];

  const int t = threadIdx.x;
  const int b = blockIdx.x;
  const int r0 = b << 7;
  const int beg = bstart[b];
  const int end = bstart[b + 1];
  const int total = end - beg;

  if (t < 128) cl[t] = 0;
  __syncthreads();
  for (int i = beg + t; i < end; i += 256) atomicAdd(&cl[ebuf[i] & 127u], 1);
  __syncthreads();

  int v = (t < 128) ? cl[t] : 0;
  sc2[t] = v; __syncthreads();
  for (int off = 1; off < 256; off <<= 1){
    int u = (t >= off) ? sc2[t - off] : 0;
    __syncthreads();
    sc2[t] += u;
    __syncthreads();
  }
  int excl = sc2[t] - v;
  if (t < 128){
    int node = r0 + t;
    if (node < n){
      rowptr[node] = beg + excl;
      dinv[node]   = rsqrtf((float)(v + 1));
    }
    cl[t] = excl;
  }
  __syncthreads();

  if (total <= STCAP){
    for (int i = beg + t; i < end; i += 256){
      unsigned u = ebuf[i];
      int p = atomicAdd(&cl[u & 127u], 1);
      stg[p] = u >> 7;
    }
    __syncthreads();
    for (int i = t; i < total; i += 256) colv[beg + i] = (int)stg[i];
  } else {
    for (int i = beg + t; i < end; i += 256){
      unsigned u = ebuf[i];
      int p = atomicAdd(&cl[u & 127u], 1);
      colv[beg + p] = (int)(u >> 7);
    }
  }
}

// ---------------- MFMA GEMM: Gs[s][i][16] = fp8( dinv[i] * (A[i,:] @ W) ) ----------------
// A: layer1 = f32 row-major; layer2 = bf16 slice-major Hs[s][i][16].
// Output G slice-major: slice s = features s*16..s*16+15, 16B per row-slice.

template<bool AF32>
__global__ __launch_bounds__(512) void k_gemm_mfma(const void* __restrict__ Ain, const float* __restrict__ W,
    const float* __restrict__ dinv, uint4* __restrict__ Gs, int n, int N)
{
  __shared__ unsigned short At[128 * 136];
  __shared__ float dl[128];

  const int t = threadIdx.x;
  const int rowBase = blockIdx.x * 128;
  const int w  = t >> 6;
  const int l  = t & 63;
  const int ln = l & 15;
  const int lg = l >> 4;

  if (t < 128){
    int gr = rowBase + t;
    dl[t] = (gr < n) ? dinv[gr] : 0.f;
  }

  #pragma unroll
  for (int i = 0; i < 4; i++){
    int flat = i * 4096 + t * 8;
    int r = flat >> 7, c = flat & 127;
    int gr = rowBase + r;
    unsigned short tmp[8];
    if constexpr (AF32){
      const float* A = (const float*)Ain;
      float4 v0 = make_float4(0.f,0.f,0.f,0.f), v1 = v0;
      if (gr < n){
        v0 = *(const float4*)(A + (size_t)gr * 128 + c);
        v1 = *(const float4*)(A + (size_t)gr * 128 + c + 4);
      }
      tmp[0]=f2bf(v0.x); tmp[1]=f2bf(v0.y); tmp[2]=f2bf(v0.z); tmp[3]=f2bf(v0.w);
      tmp[4]=f2bf(v1.x); tmp[5]=f2bf(v1.y); tmp[6]=f2bf(v1.z); tmp[7]=f2bf(v1.w);
    } else {
      const unsigned short* A = (const unsigned short*)Ain;   // bf16 slice-major
      short8 v = {};
      if (gr < n){
        int s = c >> 4, w16 = c & 15;
        v = *(const short8*)(A + ((size_t)s * N + gr) * 16 + w16);
      }
      *(short8*)tmp = v;
    }
    int g = (c >> 3) ^ (r & 7);
    *(short8*)((char*)At + r * 256 + g * 16) = *(const short8*)tmp;
  }

  bf16x8 bfr[4];
  #pragma unroll
  for (int kk = 0; kk < 4; kk++){
    short8 tmp;
    #pragma unroll
    for (int j = 0; j < 8; j++){
      float wv = W[(kk * 32 + lg * 8 + j) * 128 + (w * 16 + ln)];
      tmp[j] = (short)f2bf(wv);
    }
    bfr[kk] = __builtin_bit_cast(bf16x8, tmp);
  }

  f32x4 acc[8];
  #pragma unroll
  for (int m = 0; m < 8; m++) acc[m] = (f32x4){0.f,0.f,0.f,0.f};

  __syncthreads();

  #pragma unroll
  for (int m = 0; m < 8; m++){
    int row = m * 16 + ln;
    #pragma unroll
    for (int kk = 0; kk < 4; kk++){
      int g = (kk * 4 + lg) ^ (row & 7);
      short8 av = *(const short8*)((const char*)At + row * 256 + g * 16);
      acc[m] = __builtin_amdgcn_mfma_f32_16x16x32_bf16(
          __builtin_bit_cast(bf16x8, av), bfr[kk], acc[m], 0, 0, 0);
    }
  }

  __syncthreads();
  unsigned char* At8 = (unsigned char*)At;

  #pragma unroll
  for (int m = 0; m < 8; m++){
    #pragma unroll
    for (int r = 0; r < 4; r++){
      int row = m * 16 + lg * 4 + r;
      At8[row * 136 + w * 16 + ln] = f2e4m3(dl[row] * acc[m][r]);
    }
  }
  __syncthreads();

  #pragma unroll
  for (int j = 0; j < 2; j++){
    int idx = j * 512 + t;          // 0..1023 = 8 slices x 128 rows
    int s = idx >> 7, r = idx & 127;
    int gr = rowBase + r;
    if (gr < n)
      Gs[(size_t)s * N + gr] = *(const uint4*)(At8 + r * 136 + s * 16);
  }
}

// ---------------- SpMM, XCD-sliced: Hs[s][d][16] = bf16(relu(dinv*(sum Gs[s][src]) + b[s])) ----
// slice = blockIdx & 7 -> pinned to one XCD (round-robin dispatch); slice data = 1.6MB, L2-resident.
// 1 thread = 1 dst row; colv segment staged in LDS.

__global__ __launch_bounds__(256) void k_spmm(const uint4* __restrict__ Gs, const int* __restrict__ rowptr,
    const int* __restrict__ colv, const float* __restrict__ dinv, const float* __restrict__ bias,
    uint4* __restrict__ Hs, int n, int N)
{
  __shared__ int scol[SCAP];
  const int t = threadIdx.x;
  const int slice = blockIdx.x & 7;
  const int rg = blockIdx.x >> 3;
  const int r0 = rg * 256;
  const int rend = (r0 + 256 < n) ? r0 + 256 : n;
  const int beg = rowptr[r0];
  const int end = rowptr[rend];
  const int cnt = end - beg;
  const int stg = (cnt < SCAP) ? cnt : SCAP;
  for (int i = t; i < stg; i += 256) scol[i] = colv[beg + i];
  __syncthreads();

  const int row = r0 + t;
  if (row >= n) return;

  const uint4* Gsl = Gs + (size_t)slice * N;
  float acc[16] = {0,0,0,0,0,0,0,0,0,0,0,0,0,0,0,0};
  add16(acc, Gsl[row]);                       // self loop
  int e  = rowptr[row] - beg;
  int e1 = rowptr[row + 1] - beg;

  if (e1 <= stg){
    for (; e + 4 <= e1; e += 4){
      int s0 = scol[e], s1 = scol[e+1], s2 = scol[e+2], s3 = scol[e+3];
      uint4 v0 = Gsl[s0], v1 = Gsl[s1], v2 = Gsl[s2], v3 = Gsl[s3];
      add16(acc, v0); add16(acc, v1); add16(acc, v2); add16(acc, v3);
    }
    for (; e < e1; ++e) add16(acc, Gsl[scol[e]]);
  } else {
    for (; e < e1; ++e){
      int s = (e < stg) ? scol[e] : colv[beg + e];
      add16(acc, Gsl[s]);
    }
  }

  float dv = dinv[row];
  const float4* bp = (const float4*)(bias + slice * 16);
  float4 b0 = bp[0], b1 = bp[1], b2 = bp[2], b3v = bp[3];
  float r[16];
  r[0]=fmaxf(fmaf(dv,acc[0],b0.x),0.f);  r[1]=fmaxf(fmaf(dv,acc[1],b0.y),0.f);
  r[2]=fmaxf(fmaf(dv,acc[2],b0.z),0.f);  r[3]=fmaxf(fmaf(dv,acc[3],b0.w),0.f);
  r[4]=fmaxf(fmaf(dv,acc[4],b1.x),0.f);  r[5]=fmaxf(fmaf(dv,acc[5],b1.y),0.f);
  r[6]=fmaxf(fmaf(dv,acc[6],b1.z),0.f);  r[7]=fmaxf(fmaf(dv,acc[7],b1.w),0.f);
  r[8]=fmaxf(fmaf(dv,acc[8],b2.x),0.f);  r[9]=fmaxf(fmaf(dv,acc[9],b2.y),0.f);
  r[10]=fmaxf(fmaf(dv,acc[10],b2.z),0.f); r[11]=fmaxf(fmaf(dv,acc[11],b2.w),0.f);
  r[12]=fmaxf(fmaf(dv,acc[12],b3v.x),0.f); r[13]=fmaxf(fmaf(dv,acc[13],b3v.y),0.f);
  r[14]=fmaxf(fmaf(dv,acc[14],b3v.z),0.f); r[15]=fmaxf(fmaf(dv,acc[15],b3v.w),0.f);
  uint4 o0, o1;
  o0.x = (unsigned)f2bf(r[0])  | ((unsigned)f2bf(r[1])  << 16);
  o0.y = (unsigned)f2bf(r[2])  | ((unsigned)f2bf(r[3])  << 16);
  o0.z = (unsigned)f2bf(r[4])  | ((unsigned)f2bf(r[5])  << 16);
  o0.w = (unsigned)f2bf(r[6])  | ((unsigned)f2bf(r[7])  << 16);
  o1.x = (unsigned)f2bf(r[8])  | ((unsigned)f2bf(r[9])  << 16);
  o1.y = (unsigned)f2bf(r[10]) | ((unsigned)f2bf(r[11]) << 16);
  o1.z = (unsigned)f2bf(r[12]) | ((unsigned)f2bf(r[13]) << 16);
  o1.w = (unsigned)f2bf(r[14]) | ((unsigned)f2bf(r[15]) << 16);
  size_t hb = ((size_t)slice * N + row) * 2;
  Hs[hb]     = o0;
  Hs[hb + 1] = o1;
}

// ---------------- layer 3 ----------------

__global__ __launch_bounds__(256) void k_gemv3(const unsigned short* __restrict__ Hs, const float* __restrict__ W3,
    const float* __restrict__ dinv, float* __restrict__ tvec, int n, int N)
{
  int wid  = (blockIdx.x * 256 + threadIdx.x) >> 6;
  int lane = threadIdx.x & 63;
  if (wid >= n) return;
  int slice = lane >> 3;
  int w16 = (lane * 2) & 15;
  unsigned u = *(const unsigned*)(Hs + ((size_t)slice * N + wid) * 16 + w16);
  float2 wv = *(const float2*)(W3 + lane * 2);
  float v = bflo(u) * wv.x + bfhi(u) * wv.y;
  #pragma unroll
  for (int off = 32; off; off >>= 1) v += __shfl_xor(v, off);
  if (lane == 0) tvec[wid] = dinv[wid] * v;
}

__global__ __launch_bounds__(256) void k_final3(const float* __restrict__ tvec, const int* __restrict__ rowptr,
    const int* __restrict__ colv, const float* __restrict__ dinv, const float* __restrict__ b3,
    const float* __restrict__ x, float* __restrict__ out, int n)
{
  int tid = blockIdx.x * 256 + threadIdx.x;
  int row = tid >> 4;
  int gl  = tid & 15;
  if (row >= n) return;
  float s = 0.f;
  int e0 = rowptr[row], e1 = rowptr[row + 1];
  for (int e = e0 + gl; e < e1; e += 16) s += tvec[colv[e]];
  s += __shfl_xor(s, 1); s += __shfl_xor(s, 2);
  s += __shfl_xor(s, 4); s += __shfl_xor(s, 8);
  if (gl == 0){
    s += tvec[row];
    float v = fmaxf(fmaf(dinv[row], s, b3[0]), 0.f);
    out[row] = v + x[(size_t)row * 128 + 127];
  }
}

// ---------------- launch ----------------

extern "C" void kernel_launch(void* const* d_in, const int* in_sizes, int n_in,
                              void* d_out, int out_size, void* d_ws, size_t ws_size,
                              hipStream_t stream)
{
  const float* x  = (const float*)d_in[0];
  const int*   ei = (const int*)d_in[1];
  const float* W1 = (const float*)d_in[3];
  const float* b1 = (const float*)d_in[4];
  const float* W2 = (const float*)d_in[5];
  const float* b2 = (const float*)d_in[6];
  const float* W3 = (const float*)d_in[7];
  const float* b3 = (const float*)d_in[8];
  float* out = (float*)d_out;

  const int N = in_sizes[0] / 128;
  const int E = in_sizes[1] / 2;
  const int* src = ei;
  const int* dst = ei + E;
  const int NB = (N + 127) >> 7;

  char* wsb = (char*)d_ws;
  size_t off = 0;
  auto carve = [&](size_t bytes) -> void* {
    void* p = wsb + off;
    off += bytes;
    off = (off + 255) & ~(size_t)255;
    return p;
  };
  float*    dinv   = (float*)carve((size_t)N * 4);
  int*      rowptr = (int*)carve((size_t)(N + 1) * 4);
  int*      colv   = (int*)carve((size_t)E * 4);
  int*      bcnt   = (int*)carve((size_t)NB * 4);
  int*      bstart = (int*)carve((size_t)(NB + 1) * 4);
  int*      bpos   = (int*)carve((size_t)NB * 4);
  float*    tvec   = (float*)carve((size_t)N * 4);
  uint4*    Gs     = (uint4*)carve((size_t)N * 128);   // fp8 slice-major [8][N][16B]
  uint4*    Hs     = (uint4*)carve((size_t)N * 256);   // bf16 slice-major [8][N][32B]
  unsigned* ebuf   = (unsigned*)Hs;                     // overlay: dead before spmm1 writes Hs

  const int nrg = (N + 255) / 256;

  hipMemsetAsync(bcnt, 0, (size_t)NB * 4, stream);
  k_bcnt  <<<128, 1024, 0, stream>>>(dst, bcnt, E, NB);
  k_bscan <<<1, 1024, 0, stream>>>(bcnt, bstart, bpos, rowptr, NB, N, E);
  k_part  <<<(E + PART_C - 1) / PART_C, 1024, 0, stream>>>(src, dst, bpos, ebuf, E, NB);
  k_bsort <<<NB, 256, 0, stream>>>(ebuf, bstart, rowptr, colv, dinv, N);

  // layer 1
  k_gemm_mfma<true ><<<(N + 127) / 128, 512, 0, stream>>>(x, W1, dinv, Gs, N, N);
  k_spmm<<<nrg * 8, 256, 0, stream>>>(Gs, rowptr, colv, dinv, b1, Hs, N, N);
  // layer 2
  k_gemm_mfma<false><<<(N + 127) / 128, 512, 0, stream>>>(Hs, W2, dinv, Gs, N, N);
  k_spmm<<<nrg * 8, 256, 0, stream>>>(Gs, rowptr, colv, dinv, b2, Hs, N, N);
  // layer 3 (HID -> 1)
  k_gemv3 <<<(N + 3) / 4, 256, 0, stream>>>((const unsigned short*)Hs, W3, dinv, tvec, N, N);
  k_final3<<<((size_t)N * 16 + 255) / 256, 256, 0, stream>>>(tvec, rowptr, colv, dinv, b3, x, out, N);
}

// Round 8
// 173.209 us; speedup vs baseline: 1.3787x; 1.3787x over previous
//
#include <hip/hip_runtime.h>
#include <hip/hip_bf16.h>

typedef __attribute__((ext_vector_type(8))) short short8;
typedef __attribute__((ext_vector_type(8))) __bf16 bf16x8;
typedef __attribute__((ext_vector_type(4))) float f32x4;

static __device__ __forceinline__ float bflo(unsigned u){ return __uint_as_float(u << 16); }
static __device__ __forceinline__ float bfhi(unsigned u){ return __uint_as_float(u & 0xffff0000u); }
static __device__ __forceinline__ unsigned short f2bf(float f){
  unsigned u = __float_as_uint(f);
  unsigned r = u + 0x7fffu + ((u >> 16) & 1u);
  return (unsigned short)(r >> 16);
}

// ---- fp8 e4m3 conversions ----
#if __has_builtin(__builtin_amdgcn_cvt_pk_fp8_f32)
static __device__ __forceinline__ unsigned char f2e4m3(float f){
  return (unsigned char)(__builtin_amdgcn_cvt_pk_fp8_f32(f, 0.f, 0, false) & 0xff);
}
#else
static __device__ __forceinline__ unsigned char f2e4m3(float f){
  unsigned s = (__float_as_uint(f) >> 31) << 7;
  float a = fabsf(f);
  if (a >= 448.f) return (unsigned char)(s | 0x7e);
  if (a < 0.0009765625f) return (unsigned char)s;
  if (a >= 0.015625f){
    int e; float m = frexpf(a, &e);
    int q = (int)rintf(m * 16.f);
    int E = e - 1 + 7;
    if (q == 16){ q = 8; E++; }
    if (E >= 16) return (unsigned char)(s | 0x7e);
    return (unsigned char)(s | (E << 3) | (q - 8));
  } else {
    int q = (int)rintf(a * 512.f);
    if (q > 7) return (unsigned char)(s | 0x08);
    return (unsigned char)(s | q);
  }
}
#endif

#if __has_builtin(__builtin_amdgcn_cvt_pk_f32_fp8)
static __device__ __forceinline__ float4 e4m3x4_to_f32(unsigned u){
  auto lo = __builtin_amdgcn_cvt_pk_f32_fp8((int)u, false);
  auto hi = __builtin_amdgcn_cvt_pk_f32_fp8((int)u, true);
  return make_float4(lo[0], lo[1], hi[0], hi[1]);
}
#else
static __device__ __forceinline__ float e4m3_1(unsigned b){
  unsigned s = b >> 7, e = (b >> 3) & 15, m = b & 7;
  float v = e ? ldexpf((float)(8 + m) * 0.125f, (int)e - 7) : ldexpf((float)m * 0.125f, -6);
  return s ? -v : v;
}
static __device__ __forceinline__ float4 e4m3x4_to_f32(unsigned u){
  return make_float4(e4m3_1(u & 255), e4m3_1((u >> 8) & 255), e4m3_1((u >> 16) & 255), e4m3_1(u >> 24));
}
#endif

static __device__ __forceinline__ void add8(float* acc, uint2 u){
  float4 a = e4m3x4_to_f32(u.x), b = e4m3x4_to_f32(u.y);
  acc[0] += a.x; acc[1] += a.y; acc[2] += a.z; acc[3] += a.w;
  acc[4] += b.x; acc[5] += b.y; acc[6] += b.z; acc[7] += b.w;
}

#define NBMAX  1024
#define PART_C 4096
#define STCAP  4096
#define BCAP   6144   // per-bucket ebuf capacity (mean 2046, +90 sigma)

// ---------------- bucket pipeline (no pre-count pass) ----------------

// partition: bucket by dst>>7 into CAP-strided ebuf; bpos[b] (zero-init) tracks fill.
__global__ __launch_bounds__(1024) void k_part(const int* __restrict__ src, const int* __restrict__ dst,
    int* __restrict__ bpos, unsigned* __restrict__ ebuf, int E, int NB)
{
  __shared__ int hist[NBMAX + 1];
  __shared__ int hist2[NBMAX];
  __shared__ int gbase[NBMAX];
  __shared__ int sc[1024];
  __shared__ unsigned staged[PART_C];

  const int t = threadIdx.x;
  const int base = blockIdx.x * PART_C;

  for (int i = t; i < NBMAX; i += 1024){ hist[i] = 0; hist2[i] = 0; }
  __syncthreads();

  unsigned up[4];
  int bb[4];
  #pragma unroll
  for (int j = 0; j < 4; j++){
    int e = base + j * 1024 + t;
    if (e < E){
      int s = src[e], d = dst[e];
      bb[j] = d >> 7;
      up[j] = ((unsigned)s << 7) | (unsigned)(d & 127);
      atomicAdd(&hist[bb[j]], 1);
    } else bb[j] = -1;
  }
  __syncthreads();

  int v = (t < NB) ? hist[t] : 0;
  sc[t] = v; __syncthreads();
  for (int off = 1; off < 1024; off <<= 1){
    int u = (t >= off) ? sc[t - off] : 0;
    __syncthreads();
    sc[t] += u;
    __syncthreads();
  }
  int incl = sc[t];
  if (t < NB) hist[t] = incl - v;
  if (t == NB - 1) hist[NB] = incl;
  if (t < NB && v > 0) gbase[t] = t * BCAP + atomicAdd(&bpos[t], v);
  __syncthreads();

  #pragma unroll
  for (int j = 0; j < 4; j++){
    if (bb[j] >= 0){
      int r = atomicAdd(&hist2[bb[j]], 1);
      staged[hist[bb[j]] + r] = up[j];
    }
  }
  __syncthreads();

  int total = hist[NB];
  for (int i = t; i < total; i += 1024){
    int lo = 0, hi = NB;
    while (hi - lo > 1){
      int mid = (lo + hi) >> 1;
      if (hist[mid] <= i) lo = mid; else hi = mid;
    }
    ebuf[gbase[lo] + (i - hist[lo])] = staged[i];
  }
}

// one-block exclusive scan of final bucket counts -> bstart
__global__ __launch_bounds__(1024) void k_cscan(const int* __restrict__ cnts, int* __restrict__ bstart,
    int* __restrict__ rowptr, int NB, int N, int E){
  __shared__ int sc[1024];
  const int t = threadIdx.x;
  int v = (t < NB) ? cnts[t] : 0;
  sc[t] = v; __syncthreads();
  for (int off = 1; off < 1024; off <<= 1){
    int u = (t >= off) ? sc[t - off] : 0;
    __syncthreads();
    sc[t] += u;
    __syncthreads();
  }
  if (t < NB) bstart[t] = sc[t] - v;
  if (t == 0){ bstart[NB] = E; rowptr[N] = E; }
}

// fine sort within each 128-row bucket: read CAP-strided ebuf, write compact colv; emits rowptr+dinv
__global__ __launch_bounds__(256) void k_bsort(const unsigned* __restrict__ ebuf, const int* __restrict__ cnts,
    const int* __restrict__ bstart, int* __restrict__ rowptr, int* __restrict__ colv,
    float* __restrict__ dinv, int n)
{
  __shared__ int cl[128];
  __shared__ int sc2[256];
  __shared__ unsigned stg[STCAP];

  const int t = threadIdx.x;
  const int b = blockIdx.x;
  const int r0 = b << 7;
  const int rbeg = b * BCAP;          // read base (CAP-strided)
  const int total = cnts[b];
  const int wbeg = bstart[b];         // write base (compact)

  if (t < 128) cl[t] = 0;
  __syncthreads();
  for (int i = t; i < total; i += 256) atomicAdd(&cl[ebuf[rbeg + i] & 127u], 1);
  __syncthreads();

  int v = (t < 128) ? cl[t] : 0;
  sc2[t] = v; __syncthreads();
  for (int off = 1; off < 256; off <<= 1){
    int u = (t >= off) ? sc2[t - off] : 0;
    __syncthreads();
    sc2[t] += u;
    __syncthreads();
  }
  int excl = sc2[t] - v;
  if (t < 128){
    int node = r0 + t;
    if (node < n){
      rowptr[node] = wbeg + excl;
      dinv[node]   = rsqrtf((float)(v + 1));
    }
    cl[t] = excl;
  }
  __syncthreads();

  if (total <= STCAP){
    for (int i = t; i < total; i += 256){
      unsigned u = ebuf[rbeg + i];
      int p = atomicAdd(&cl[u & 127u], 1);
      stg[p] = u >> 7;
    }
    __syncthreads();
    for (int i = t; i < total; i += 256) colv[wbeg + i] = (int)stg[i];
  } else {
    for (int i = t; i < total; i += 256){
      unsigned u = ebuf[rbeg + i];
      int p = atomicAdd(&cl[u & 127u], 1);
      colv[wbeg + p] = (int)(u >> 7);
    }
  }
}

// ---------------- MFMA GEMM: G8[i,:] = fp8( dinv[i] * (A[i,:] @ W) ) ----------------

template<bool AF32>
__global__ __launch_bounds__(512) void k_gemm_mfma(const void* __restrict__ Ain, const float* __restrict__ W,
    const float* __restrict__ dinv, unsigned char* __restrict__ G8, int n)
{
  __shared__ unsigned short At[128 * 136];
  __shared__ float dl[128];

  const int t = threadIdx.x;
  const int rowBase = blockIdx.x * 128;
  const int w  = t >> 6;
  const int l  = t & 63;
  const int ln = l & 15;
  const int lg = l >> 4;

  if (t < 128){
    int gr = rowBase + t;
    dl[t] = (gr < n) ? dinv[gr] : 0.f;
  }

  #pragma unroll
  for (int i = 0; i < 4; i++){
    int flat = i * 4096 + t * 8;
    int r = flat >> 7, c = flat & 127;
    int gr = rowBase + r;
    unsigned short tmp[8];
    if constexpr (AF32){
      const float* A = (const float*)Ain;
      float4 v0 = make_float4(0.f,0.f,0.f,0.f), v1 = v0;
      if (gr < n){
        v0 = *(const float4*)(A + (size_t)gr * 128 + c);
        v1 = *(const float4*)(A + (size_t)gr * 128 + c + 4);
      }
      tmp[0]=f2bf(v0.x); tmp[1]=f2bf(v0.y); tmp[2]=f2bf(v0.z); tmp[3]=f2bf(v0.w);
      tmp[4]=f2bf(v1.x); tmp[5]=f2bf(v1.y); tmp[6]=f2bf(v1.z); tmp[7]=f2bf(v1.w);
    } else {
      const unsigned short* A = (const unsigned short*)Ain;
      short8 v = {};
      if (gr < n) v = *(const short8*)(A + (size_t)gr * 128 + c);
      *(short8*)tmp = v;
    }
    int g = (c >> 3) ^ (r & 7);
    *(short8*)((char*)At + r * 256 + g * 16) = *(const short8*)tmp;
  }

  bf16x8 bfr[4];
  #pragma unroll
  for (int kk = 0; kk < 4; kk++){
    short8 tmp;
    #pragma unroll
    for (int j = 0; j < 8; j++){
      float wv = W[(kk * 32 + lg * 8 + j) * 128 + (w * 16 + ln)];
      tmp[j] = (short)f2bf(wv);
    }
    bfr[kk] = __builtin_bit_cast(bf16x8, tmp);
  }

  f32x4 acc[8];
  #pragma unroll
  for (int m = 0; m < 8; m++) acc[m] = (f32x4){0.f,0.f,0.f,0.f};

  __syncthreads();

  #pragma unroll
  for (int m = 0; m < 8; m++){
    int row = m * 16 + ln;
    #pragma unroll
    for (int kk = 0; kk < 4; kk++){
      int g = (kk * 4 + lg) ^ (row & 7);
      short8 av = *(const short8*)((const char*)At + row * 256 + g * 16);
      acc[m] = __builtin_amdgcn_mfma_f32_16x16x32_bf16(
          __builtin_bit_cast(bf16x8, av), bfr[kk], acc[m], 0, 0, 0);
    }
  }

  __syncthreads();
  unsigned char* At8 = (unsigned char*)At;

  #pragma unroll
  for (int m = 0; m < 8; m++){
    #pragma unroll
    for (int r = 0; r < 4; r++){
      int row = m * 16 + lg * 4 + r;
      At8[row * 136 + w * 16 + ln] = f2e4m3(dl[row] * acc[m][r]);
    }
  }
  __syncthreads();

  {
    int r = t >> 2, c = (t & 3) * 32;
    int gr = rowBase + r;
    if (gr < n){
      uint4 a = *(const uint4*)(At8 + r * 136 + c);
      uint4 b = *(const uint4*)(At8 + r * 136 + c + 16);
      *(uint4*)(G8 + (size_t)gr * 128 + c)      = a;
      *(uint4*)(G8 + (size_t)gr * 128 + c + 16) = b;
    }
  }
}

// ---------------- SpMM: H(bf16) = relu( dinv*(gather-sum fp8) + b ) ----------------
// 16 lanes per row (uint2 = 8 fp8/lane); 4 rows per wave; unroll tiers 8/4/1.

__global__ __launch_bounds__(256) void k_spmm(const uint2* __restrict__ G8, const int* __restrict__ rowptr,
    const int* __restrict__ colv, const float* __restrict__ dinv, const float* __restrict__ bias,
    unsigned* __restrict__ H, int n)
{
  int tid = blockIdx.x * 256 + threadIdx.x;
  int row = tid >> 4;
  int gl  = tid & 15;
  if (row >= n) return;

  float acc[8] = {0,0,0,0,0,0,0,0};
  add8(acc, G8[(size_t)row * 16 + gl]);         // self loop
  int e = rowptr[row], e1 = rowptr[row + 1];

  for (; e + 8 <= e1; e += 8){
    int s0 = colv[e    ], s1 = colv[e + 1], s2 = colv[e + 2], s3 = colv[e + 3];
    int s4 = colv[e + 4], s5 = colv[e + 5], s6 = colv[e + 6], s7 = colv[e + 7];
    uint2 v0 = G8[(size_t)s0 * 16 + gl];
    uint2 v1 = G8[(size_t)s1 * 16 + gl];
    uint2 v2 = G8[(size_t)s2 * 16 + gl];
    uint2 v3 = G8[(size_t)s3 * 16 + gl];
    uint2 v4 = G8[(size_t)s4 * 16 + gl];
    uint2 v5 = G8[(size_t)s5 * 16 + gl];
    uint2 v6 = G8[(size_t)s6 * 16 + gl];
    uint2 v7 = G8[(size_t)s7 * 16 + gl];
    add8(acc, v0); add8(acc, v1); add8(acc, v2); add8(acc, v3);
    add8(acc, v4); add8(acc, v5); add8(acc, v6); add8(acc, v7);
  }
  for (; e + 4 <= e1; e += 4){
    int s0 = colv[e], s1 = colv[e + 1], s2 = colv[e + 2], s3 = colv[e + 3];
    uint2 v0 = G8[(size_t)s0 * 16 + gl];
    uint2 v1 = G8[(size_t)s1 * 16 + gl];
    uint2 v2 = G8[(size_t)s2 * 16 + gl];
    uint2 v3 = G8[(size_t)s3 * 16 + gl];
    add8(acc, v0); add8(acc, v1); add8(acc, v2); add8(acc, v3);
  }
  for (; e < e1; ++e) add8(acc, G8[(size_t)colv[e] * 16 + gl]);

  float dv = dinv[row];
  float4 b0 = *(const float4*)(bias + gl * 8);
  float4 b1 = *(const float4*)(bias + gl * 8 + 4);
  float r0 = fmaxf(fmaf(dv, acc[0], b0.x), 0.f);
  float r1 = fmaxf(fmaf(dv, acc[1], b0.y), 0.f);
  float r2 = fmaxf(fmaf(dv, acc[2], b0.z), 0.f);
  float r3 = fmaxf(fmaf(dv, acc[3], b0.w), 0.f);
  float r4 = fmaxf(fmaf(dv, acc[4], b1.x), 0.f);
  float r5 = fmaxf(fmaf(dv, acc[5], b1.y), 0.f);
  float r6 = fmaxf(fmaf(dv, acc[6], b1.z), 0.f);
  float r7 = fmaxf(fmaf(dv, acc[7], b1.w), 0.f);
  uint4 o;
  o.x = (unsigned)f2bf(r0) | ((unsigned)f2bf(r1) << 16);
  o.y = (unsigned)f2bf(r2) | ((unsigned)f2bf(r3) << 16);
  o.z = (unsigned)f2bf(r4) | ((unsigned)f2bf(r5) << 16);
  o.w = (unsigned)f2bf(r6) | ((unsigned)f2bf(r7) << 16);
  *(uint4*)(H + (size_t)row * 64 + gl * 4) = o;
}

// ---------------- layer 3 ----------------

__global__ __launch_bounds__(256) void k_gemv3(const unsigned* __restrict__ H, const float* __restrict__ W3,
    const float* __restrict__ dinv, float* __restrict__ tvec, int n)
{
  int wid  = (blockIdx.x * 256 + threadIdx.x) >> 6;
  int lane = threadIdx.x & 63;
  if (wid >= n) return;
  unsigned u = H[(size_t)wid * 64 + lane];
  float2 wv = *(const float2*)(W3 + lane * 2);
  float v = bflo(u) * wv.x + bfhi(u) * wv.y;
  #pragma unroll
  for (int off = 32; off; off >>= 1) v += __shfl_xor(v, off);
  if (lane == 0) tvec[wid] = dinv[wid] * v;
}

__global__ __launch_bounds__(256) void k_final3(const float* __restrict__ tvec, const int* __restrict__ rowptr,
    const int* __restrict__ colv, const float* __restrict__ dinv, const float* __restrict__ b3,
    const float* __restrict__ x, float* __restrict__ out, int n)
{
  int tid = blockIdx.x * 256 + threadIdx.x;
  int row = tid >> 4;
  int gl  = tid & 15;
  if (row >= n) return;
  float s = 0.f;
  int e0 = rowptr[row], e1 = rowptr[row + 1];
  for (int e = e0 + gl; e < e1; e += 16) s += tvec[colv[e]];
  s += __shfl_xor(s, 1); s += __shfl_xor(s, 2);
  s += __shfl_xor(s, 4); s += __shfl_xor(s, 8);
  if (gl == 0){
    s += tvec[row];
    float v = fmaxf(fmaf(dinv[row], s, b3[0]), 0.f);
    out[row] = v + x[(size_t)row * 128 + 127];
  }
}

// ---------------- launch ----------------

extern "C" void kernel_launch(void* const* d_in, const int* in_sizes, int n_in,
                              void* d_out, int out_size, void* d_ws, size_t ws_size,
                              hipStream_t stream)
{
  const float* x  = (const float*)d_in[0];
  const int*   ei = (const int*)d_in[1];
  const float* W1 = (const float*)d_in[3];
  const float* b1 = (const float*)d_in[4];
  const float* W2 = (const float*)d_in[5];
  const float* b2 = (const float*)d_in[6];
  const float* W3 = (const float*)d_in[7];
  const float* b3 = (const float*)d_in[8];
  float* out = (float*)d_out;

  const int N = in_sizes[0] / 128;
  const int E = in_sizes[1] / 2;
  const int* src = ei;
  const int* dst = ei + E;
  const int NB = (N + 127) >> 7;

  char* wsb = (char*)d_ws;
  size_t off = 0;
  auto carve = [&](size_t bytes) -> void* {
    void* p = wsb + off;
    off += bytes;
    off = (off + 255) & ~(size_t)255;
    return p;
  };
  float*    dinv   = (float*)carve((size_t)N * 4);
  int*      rowptr = (int*)carve((size_t)(N + 1) * 4);
  int*      colv   = (int*)carve((size_t)E * 4);
  int*      bstart = (int*)carve((size_t)(NB + 1) * 4);
  int*      bpos   = (int*)carve((size_t)NB * 4);
  float*    tvec   = (float*)carve((size_t)N * 4);
  unsigned char* G8 = (unsigned char*)carve((size_t)N * 128);  // fp8 N x 128
  unsigned* H      = (unsigned*)carve((size_t)N * 256);        // bf16 N x 128
  unsigned* ebuf   = (unsigned*)H;                             // overlay: NB*BCAP*4 <= N*256

  hipMemsetAsync(bpos, 0, (size_t)NB * 4, stream);
  k_part  <<<(E + PART_C - 1) / PART_C, 1024, 0, stream>>>(src, dst, bpos, ebuf, E, NB);
  k_cscan <<<1, 1024, 0, stream>>>(bpos, bstart, rowptr, NB, N, E);
  k_bsort <<<NB, 256, 0, stream>>>(ebuf, bpos, bstart, rowptr, colv, dinv, N);

  // layer 1
  k_gemm_mfma<true ><<<(N + 127) / 128, 512, 0, stream>>>(x, W1, dinv, G8, N);
  k_spmm<<<((size_t)N * 16 + 255) / 256, 256, 0, stream>>>((const uint2*)G8, rowptr, colv, dinv, b1, H, N);
  // layer 2
  k_gemm_mfma<false><<<(N + 127) / 128, 512, 0, stream>>>(H, W2, dinv, G8, N);
  k_spmm<<<((size_t)N * 16 + 255) / 256, 256, 0, stream>>>((const uint2*)G8, rowptr, colv, dinv, b2, H, N);
  // layer 3 (HID -> 1)
  k_gemv3 <<<(N + 3) / 4, 256, 0, stream>>>(H, W3, dinv, tvec, N);
  k_final3<<<((size_t)N * 16 + 255) / 256, 256, 0, stream>>>(tvec, rowptr, colv, dinv, b3, x, out, N);
}

// Round 9
// 167.615 us; speedup vs baseline: 1.4247x; 1.0334x over previous
//
#include <hip/hip_runtime.h>
#include <hip/hip_bf16.h>

typedef __attribute__((ext_vector_type(8))) short short8;
typedef __attribute__((ext_vector_type(8))) __bf16 bf16x8;
typedef __attribute__((ext_vector_type(4))) float f32x4;

static __device__ __forceinline__ float bflo(unsigned u){ return __uint_as_float(u << 16); }
static __device__ __forceinline__ float bfhi(unsigned u){ return __uint_as_float(u & 0xffff0000u); }
static __device__ __forceinline__ unsigned short f2bf(float f){
  unsigned u = __float_as_uint(f);
  unsigned r = u + 0x7fffu + ((u >> 16) & 1u);
  return (unsigned short)(r >> 16);
}

// ---- fp8 e4m3 conversions ----
#if __has_builtin(__builtin_amdgcn_cvt_pk_fp8_f32)
static __device__ __forceinline__ unsigned char f2e4m3(float f){
  return (unsigned char)(__builtin_amdgcn_cvt_pk_fp8_f32(f, 0.f, 0, false) & 0xff);
}
#else
static __device__ __forceinline__ unsigned char f2e4m3(float f){
  unsigned s = (__float_as_uint(f) >> 31) << 7;
  float a = fabsf(f);
  if (a >= 448.f) return (unsigned char)(s | 0x7e);
  if (a < 0.0009765625f) return (unsigned char)s;
  if (a >= 0.015625f){
    int e; float m = frexpf(a, &e);
    int q = (int)rintf(m * 16.f);
    int E = e - 1 + 7;
    if (q == 16){ q = 8; E++; }
    if (E >= 16) return (unsigned char)(s | 0x7e);
    return (unsigned char)(s | (E << 3) | (q - 8));
  } else {
    int q = (int)rintf(a * 512.f);
    if (q > 7) return (unsigned char)(s | 0x08);
    return (unsigned char)(s | q);
  }
}
#endif

#if __has_builtin(__builtin_amdgcn_cvt_pk_f32_fp8)
static __device__ __forceinline__ float4 e4m3x4_to_f32(unsigned u){
  auto lo = __builtin_amdgcn_cvt_pk_f32_fp8((int)u, false);
  auto hi = __builtin_amdgcn_cvt_pk_f32_fp8((int)u, true);
  return make_float4(lo[0], lo[1], hi[0], hi[1]);
}
#else
static __device__ __forceinline__ float e4m3_1(unsigned b){
  unsigned s = b >> 7, e = (b >> 3) & 15, m = b & 7;
  float v = e ? ldexpf((float)(8 + m) * 0.125f, (int)e - 7) : ldexpf((float)m * 0.125f, -6);
  return s ? -v : v;
}
static __device__ __forceinline__ float4 e4m3x4_to_f32(unsigned u){
  return make_float4(e4m3_1(u & 255), e4m3_1((u >> 8) & 255), e4m3_1((u >> 16) & 255), e4m3_1(u >> 24));
}
#endif

static __device__ __forceinline__ void add16(float* a, uint4 v){
  float4 f0 = e4m3x4_to_f32(v.x), f1 = e4m3x4_to_f32(v.y);
  float4 f2 = e4m3x4_to_f32(v.z), f3 = e4m3x4_to_f32(v.w);
  a[0]+=f0.x; a[1]+=f0.y; a[2]+=f0.z; a[3]+=f0.w;
  a[4]+=f1.x; a[5]+=f1.y; a[6]+=f1.z; a[7]+=f1.w;
  a[8]+=f2.x; a[9]+=f2.y; a[10]+=f2.z; a[11]+=f2.w;
  a[12]+=f3.x; a[13]+=f3.y; a[14]+=f3.z; a[15]+=f3.w;
}

#define NBMAX  1024
#define PART_C 4096
#define STCAP  4096
#define BCAP   6144   // per-bucket ebuf capacity (mean 2046, +90 sigma)

// ---------------- bucket pipeline (no pre-count pass) ----------------

__global__ __launch_bounds__(1024) void k_part(const int* __restrict__ src, const int* __restrict__ dst,
    int* __restrict__ bpos, unsigned* __restrict__ ebuf, int E, int NB)
{
  __shared__ int hist[NBMAX + 1];
  __shared__ int hist2[NBMAX];
  __shared__ int gbase[NBMAX];
  __shared__ int sc[1024];
  __shared__ unsigned staged[PART_C];

  const int t = threadIdx.x;
  const int base = blockIdx.x * PART_C;

  for (int i = t; i < NBMAX; i += 1024){ hist[i] = 0; hist2[i] = 0; }
  __syncthreads();

  unsigned up[4];
  int bb[4];
  #pragma unroll
  for (int j = 0; j < 4; j++){
    int e = base + j * 1024 + t;
    if (e < E){
      int s = src[e], d = dst[e];
      bb[j] = d >> 7;
      up[j] = ((unsigned)s << 7) | (unsigned)(d & 127);
      atomicAdd(&hist[bb[j]], 1);
    } else bb[j] = -1;
  }
  __syncthreads();

  int v = (t < NB) ? hist[t] : 0;
  sc[t] = v; __syncthreads();
  for (int off = 1; off < 1024; off <<= 1){
    int u = (t >= off) ? sc[t - off] : 0;
    __syncthreads();
    sc[t] += u;
    __syncthreads();
  }
  int incl = sc[t];
  if (t < NB) hist[t] = incl - v;
  if (t == NB - 1) hist[NB] = incl;
  if (t < NB && v > 0) gbase[t] = t * BCAP + atomicAdd(&bpos[t], v);
  __syncthreads();

  #pragma unroll
  for (int j = 0; j < 4; j++){
    if (bb[j] >= 0){
      int r = atomicAdd(&hist2[bb[j]], 1);
      staged[hist[bb[j]] + r] = up[j];
    }
  }
  __syncthreads();

  int total = hist[NB];
  for (int i = t; i < total; i += 1024){
    int lo = 0, hi = NB;
    while (hi - lo > 1){
      int mid = (lo + hi) >> 1;
      if (hist[mid] <= i) lo = mid; else hi = mid;
    }
    ebuf[gbase[lo] + (i - hist[lo])] = staged[i];
  }
}

__global__ __launch_bounds__(1024) void k_cscan(const int* __restrict__ cnts, int* __restrict__ bstart,
    int* __restrict__ rowptr, int NB, int N, int E){
  __shared__ int sc[1024];
  const int t = threadIdx.x;
  int v = (t < NB) ? cnts[t] : 0;
  sc[t] = v; __syncthreads();
  for (int off = 1; off < 1024; off <<= 1){
    int u = (t >= off) ? sc[t - off] : 0;
    __syncthreads();
    sc[t] += u;
    __syncthreads();
  }
  if (t < NB) bstart[t] = sc[t] - v;
  if (t == 0){ bstart[NB] = E; rowptr[N] = E; }
}

__global__ __launch_bounds__(256) void k_bsort(const unsigned* __restrict__ ebuf, const int* __restrict__ cnts,
    const int* __restrict__ bstart, int* __restrict__ rowptr, int* __restrict__ colv,
    float* __restrict__ dinv, int n)
{
  __shared__ int cl[128];
  __shared__ int sc2[256];
  __shared__ unsigned stg[STCAP];

  const int t = threadIdx.x;
  const int b = blockIdx.x;
  const int r0 = b << 7;
  const int rbeg = b * BCAP;
  const int total = cnts[b];
  const int wbeg = bstart[b];

  if (t < 128) cl[t] = 0;
  __syncthreads();
  for (int i = t; i < total; i += 256) atomicAdd(&cl[ebuf[rbeg + i] & 127u], 1);
  __syncthreads();

  int v = (t < 128) ? cl[t] : 0;
  sc2[t] = v; __syncthreads();
  for (int off = 1; off < 256; off <<= 1){
    int u = (t >= off) ? sc2[t - off] : 0;
    __syncthreads();
    sc2[t] += u;
    __syncthreads();
  }
  int excl = sc2[t] - v;
  if (t < 128){
    int node = r0 + t;
    if (node < n){
      rowptr[node] = wbeg + excl;
      dinv[node]   = rsqrtf((float)(v + 1));
    }
    cl[t] = excl;
  }
  __syncthreads();

  if (total <= STCAP){
    for (int i = t; i < total; i += 256){
      unsigned u = ebuf[rbeg + i];
      int p = atomicAdd(&cl[u & 127u], 1);
      stg[p] = u >> 7;
    }
    __syncthreads();
    for (int i = t; i < total; i += 256) colv[wbeg + i] = (int)stg[i];
  } else {
    for (int i = t; i < total; i += 256){
      unsigned u = ebuf[rbeg + i];
      int p = atomicAdd(&cl[u & 127u], 1);
      colv[wbeg + p] = (int)(u >> 7);
    }
  }
}

// ---------------- MFMA GEMM: G8[i,:] = fp8( dinv[i] * (A[i,:] @ W) ) ----------------

template<bool AF32>
__global__ __launch_bounds__(512) void k_gemm_mfma(const void* __restrict__ Ain, const float* __restrict__ W,
    const float* __restrict__ dinv, unsigned char* __restrict__ G8, int n)
{
  __shared__ unsigned short At[128 * 136];
  __shared__ float dl[128];

  const int t = threadIdx.x;
  const int rowBase = blockIdx.x * 128;
  const int w  = t >> 6;
  const int l  = t & 63;
  const int ln = l & 15;
  const int lg = l >> 4;

  if (t < 128){
    int gr = rowBase + t;
    dl[t] = (gr < n) ? dinv[gr] : 0.f;
  }

  #pragma unroll
  for (int i = 0; i < 4; i++){
    int flat = i * 4096 + t * 8;
    int r = flat >> 7, c = flat & 127;
    int gr = rowBase + r;
    unsigned short tmp[8];
    if constexpr (AF32){
      const float* A = (const float*)Ain;
      float4 v0 = make_float4(0.f,0.f,0.f,0.f), v1 = v0;
      if (gr < n){
        v0 = *(const float4*)(A + (size_t)gr * 128 + c);
        v1 = *(const float4*)(A + (size_t)gr * 128 + c + 4);
      }
      tmp[0]=f2bf(v0.x); tmp[1]=f2bf(v0.y); tmp[2]=f2bf(v0.z); tmp[3]=f2bf(v0.w);
      tmp[4]=f2bf(v1.x); tmp[5]=f2bf(v1.y); tmp[6]=f2bf(v1.z); tmp[7]=f2bf(v1.w);
    } else {
      const unsigned short* A = (const unsigned short*)Ain;
      short8 v = {};
      if (gr < n) v = *(const short8*)(A + (size_t)gr * 128 + c);
      *(short8*)tmp = v;
    }
    int g = (c >> 3) ^ (r & 7);
    *(short8*)((char*)At + r * 256 + g * 16) = *(const short8*)tmp;
  }

  bf16x8 bfr[4];
  #pragma unroll
  for (int kk = 0; kk < 4; kk++){
    short8 tmp;
    #pragma unroll
    for (int j = 0; j < 8; j++){
      float wv = W[(kk * 32 + lg * 8 + j) * 128 + (w * 16 + ln)];
      tmp[j] = (short)f2bf(wv);
    }
    bfr[kk] = __builtin_bit_cast(bf16x8, tmp);
  }

  f32x4 acc[8];
  #pragma unroll
  for (int m = 0; m < 8; m++) acc[m] = (f32x4){0.f,0.f,0.f,0.f};

  __syncthreads();

  #pragma unroll
  for (int m = 0; m < 8; m++){
    int row = m * 16 + ln;
    #pragma unroll
    for (int kk = 0; kk < 4; kk++){
      int g = (kk * 4 + lg) ^ (row & 7);
      short8 av = *(const short8*)((const char*)At + row * 256 + g * 16);
      acc[m] = __builtin_amdgcn_mfma_f32_16x16x32_bf16(
          __builtin_bit_cast(bf16x8, av), bfr[kk], acc[m], 0, 0, 0);
    }
  }

  __syncthreads();
  unsigned char* At8 = (unsigned char*)At;

  #pragma unroll
  for (int m = 0; m < 8; m++){
    #pragma unroll
    for (int r = 0; r < 4; r++){
      int row = m * 16 + lg * 4 + r;
      At8[row * 136 + w * 16 + ln] = f2e4m3(dl[row] * acc[m][r]);
    }
  }
  __syncthreads();

  {
    int r = t >> 2, c = (t & 3) * 32;
    int gr = rowBase + r;
    if (gr < n){
      uint4 a = *(const uint4*)(At8 + r * 136 + c);
      uint4 b = *(const uint4*)(At8 + r * 136 + c + 16);
      *(uint4*)(G8 + (size_t)gr * 128 + c)      = a;
      *(uint4*)(G8 + (size_t)gr * 128 + c + 16) = b;
    }
  }
}

// ---------------- SpMM: 8 lanes/row, uint4 (16 fp8) per lane ----------------
// LAST=false: H(bf16) = relu(dinv*agg + b)
// LAST=true : tvec[row] = dinv * dot(relu(dinv*agg + b), W3)   (H never materialized)

template<bool LAST>
__global__ __launch_bounds__(256) void k_spmm(const uint4* __restrict__ G8, const int* __restrict__ rowptr,
    const int* __restrict__ colv, const float* __restrict__ dinv, const float* __restrict__ bias,
    const float* __restrict__ W3, unsigned* __restrict__ H, float* __restrict__ tvec, int n)
{
  int tid = blockIdx.x * 256 + threadIdx.x;
  int row = tid >> 3;
  int gl  = tid & 7;
  if (row >= n) return;

  float acc[16] = {0,0,0,0,0,0,0,0,0,0,0,0,0,0,0,0};
  add16(acc, G8[(size_t)row * 8 + gl]);         // self loop
  int e = rowptr[row], e1 = rowptr[row + 1];

  for (; e + 8 <= e1; e += 8){
    int s0 = colv[e    ], s1 = colv[e + 1], s2 = colv[e + 2], s3 = colv[e + 3];
    int s4 = colv[e + 4], s5 = colv[e + 5], s6 = colv[e + 6], s7 = colv[e + 7];
    uint4 v0 = G8[(size_t)s0 * 8 + gl];
    uint4 v1 = G8[(size_t)s1 * 8 + gl];
    uint4 v2 = G8[(size_t)s2 * 8 + gl];
    uint4 v3 = G8[(size_t)s3 * 8 + gl];
    uint4 v4 = G8[(size_t)s4 * 8 + gl];
    uint4 v5 = G8[(size_t)s5 * 8 + gl];
    uint4 v6 = G8[(size_t)s6 * 8 + gl];
    uint4 v7 = G8[(size_t)s7 * 8 + gl];
    add16(acc, v0); add16(acc, v1); add16(acc, v2); add16(acc, v3);
    add16(acc, v4); add16(acc, v5); add16(acc, v6); add16(acc, v7);
  }
  for (; e + 4 <= e1; e += 4){
    int s0 = colv[e], s1 = colv[e + 1], s2 = colv[e + 2], s3 = colv[e + 3];
    uint4 v0 = G8[(size_t)s0 * 8 + gl];
    uint4 v1 = G8[(size_t)s1 * 8 + gl];
    uint4 v2 = G8[(size_t)s2 * 8 + gl];
    uint4 v3 = G8[(size_t)s3 * 8 + gl];
    add16(acc, v0); add16(acc, v1); add16(acc, v2); add16(acc, v3);
  }
  for (; e < e1; ++e) add16(acc, G8[(size_t)colv[e] * 8 + gl]);

  float dv = dinv[row];
  float r[16];
  {
    const float4* bp = (const float4*)(bias + gl * 16);
    float4 b0 = bp[0], b1 = bp[1], b2 = bp[2], b3 = bp[3];
    r[0] = fmaxf(fmaf(dv, acc[0],  b0.x), 0.f);
    r[1] = fmaxf(fmaf(dv, acc[1],  b0.y), 0.f);
    r[2] = fmaxf(fmaf(dv, acc[2],  b0.z), 0.f);
    r[3] = fmaxf(fmaf(dv, acc[3],  b0.w), 0.f);
    r[4] = fmaxf(fmaf(dv, acc[4],  b1.x), 0.f);
    r[5] = fmaxf(fmaf(dv, acc[5],  b1.y), 0.f);
    r[6] = fmaxf(fmaf(dv, acc[6],  b1.z), 0.f);
    r[7] = fmaxf(fmaf(dv, acc[7],  b1.w), 0.f);
    r[8] = fmaxf(fmaf(dv, acc[8],  b2.x), 0.f);
    r[9] = fmaxf(fmaf(dv, acc[9],  b2.y), 0.f);
    r[10]= fmaxf(fmaf(dv, acc[10], b2.z), 0.f);
    r[11]= fmaxf(fmaf(dv, acc[11], b2.w), 0.f);
    r[12]= fmaxf(fmaf(dv, acc[12], b3.x), 0.f);
    r[13]= fmaxf(fmaf(dv, acc[13], b3.y), 0.f);
    r[14]= fmaxf(fmaf(dv, acc[14], b3.z), 0.f);
    r[15]= fmaxf(fmaf(dv, acc[15], b3.w), 0.f);
  }

  if constexpr (!LAST){
    uint4 o0, o1;
    o0.x = (unsigned)f2bf(r[0])  | ((unsigned)f2bf(r[1])  << 16);
    o0.y = (unsigned)f2bf(r[2])  | ((unsigned)f2bf(r[3])  << 16);
    o0.z = (unsigned)f2bf(r[4])  | ((unsigned)f2bf(r[5])  << 16);
    o0.w = (unsigned)f2bf(r[6])  | ((unsigned)f2bf(r[7])  << 16);
    o1.x = (unsigned)f2bf(r[8])  | ((unsigned)f2bf(r[9])  << 16);
    o1.y = (unsigned)f2bf(r[10]) | ((unsigned)f2bf(r[11]) << 16);
    o1.z = (unsigned)f2bf(r[12]) | ((unsigned)f2bf(r[13]) << 16);
    o1.w = (unsigned)f2bf(r[14]) | ((unsigned)f2bf(r[15]) << 16);
    *(uint4*)(H + (size_t)row * 64 + gl * 8)     = o0;
    *(uint4*)(H + (size_t)row * 64 + gl * 8 + 4) = o1;
  } else {
    const float4* wp = (const float4*)(W3 + gl * 16);
    float4 w0 = wp[0], w1 = wp[1], w2 = wp[2], w3 = wp[3];
    float s = r[0]*w0.x + r[1]*w0.y + r[2]*w0.z + r[3]*w0.w
            + r[4]*w1.x + r[5]*w1.y + r[6]*w1.z + r[7]*w1.w
            + r[8]*w2.x + r[9]*w2.y + r[10]*w2.z + r[11]*w2.w
            + r[12]*w3.x + r[13]*w3.y + r[14]*w3.z + r[15]*w3.w;
    s += __shfl_xor(s, 1); s += __shfl_xor(s, 2); s += __shfl_xor(s, 4);
    if (gl == 0) tvec[row] = dv * s;
  }
}

// ---------------- layer 3 final ----------------

__global__ __launch_bounds__(256) void k_final3(const float* __restrict__ tvec, const int* __restrict__ rowptr,
    const int* __restrict__ colv, const float* __restrict__ dinv, const float* __restrict__ b3,
    const float* __restrict__ x, float* __restrict__ out, int n)
{
  int tid = blockIdx.x * 256 + threadIdx.x;
  int row = tid >> 4;
  int gl  = tid & 15;
  if (row >= n) return;
  float s = 0.f;
  int e0 = rowptr[row], e1 = rowptr[row + 1];
  for (int e = e0 + gl; e < e1; e += 16) s += tvec[colv[e]];
  s += __shfl_xor(s, 1); s += __shfl_xor(s, 2);
  s += __shfl_xor(s, 4); s += __shfl_xor(s, 8);
  if (gl == 0){
    s += tvec[row];
    float v = fmaxf(fmaf(dinv[row], s, b3[0]), 0.f);
    out[row] = v + x[(size_t)row * 128 + 127];
  }
}

// ---------------- launch ----------------

extern "C" void kernel_launch(void* const* d_in, const int* in_sizes, int n_in,
                              void* d_out, int out_size, void* d_ws, size_t ws_size,
                              hipStream_t stream)
{
  const float* x  = (const float*)d_in[0];
  const int*   ei = (const int*)d_in[1];
  const float* W1 = (const float*)d_in[3];
  const float* b1 = (const float*)d_in[4];
  const float* W2 = (const float*)d_in[5];
  const float* b2 = (const float*)d_in[6];
  const float* W3 = (const float*)d_in[7];
  const float* b3 = (const float*)d_in[8];
  float* out = (float*)d_out;

  const int N = in_sizes[0] / 128;
  const int E = in_sizes[1] / 2;
  const int* src = ei;
  const int* dst = ei + E;
  const int NB = (N + 127) >> 7;

  char* wsb = (char*)d_ws;
  size_t off = 0;
  auto carve = [&](size_t bytes) -> void* {
    void* p = wsb + off;
    off += bytes;
    off = (off + 255) & ~(size_t)255;
    return p;
  };
  float*    dinv   = (float*)carve((size_t)N * 4);
  int*      rowptr = (int*)carve((size_t)(N + 1) * 4);
  int*      colv   = (int*)carve((size_t)E * 4);
  int*      bstart = (int*)carve((size_t)(NB + 1) * 4);
  int*      bpos   = (int*)carve((size_t)NB * 4);
  float*    tvec   = (float*)carve((size_t)N * 4);
  unsigned char* G8 = (unsigned char*)carve((size_t)N * 128);  // fp8 N x 128
  unsigned* H      = (unsigned*)carve((size_t)N * 256);        // bf16 N x 128 (layer1 only)
  unsigned* ebuf   = (unsigned*)H;                             // overlay: NB*BCAP*4 <= N*256

  hipMemsetAsync(bpos, 0, (size_t)NB * 4, stream);
  k_part  <<<(E + PART_C - 1) / PART_C, 1024, 0, stream>>>(src, dst, bpos, ebuf, E, NB);
  k_cscan <<<1, 1024, 0, stream>>>(bpos, bstart, rowptr, NB, N, E);
  k_bsort <<<NB, 256, 0, stream>>>(ebuf, bpos, bstart, rowptr, colv, dinv, N);

  // layer 1
  k_gemm_mfma<true ><<<(N + 127) / 128, 512, 0, stream>>>(x, W1, dinv, G8, N);
  k_spmm<false><<<((size_t)N * 8 + 255) / 256, 256, 0, stream>>>((const uint4*)G8, rowptr, colv, dinv, b1, nullptr, H, nullptr, N);
  // layer 2
  k_gemm_mfma<false><<<(N + 127) / 128, 512, 0, stream>>>(H, W2, dinv, G8, N);
  // layer 2 aggregation fused with layer-3 GEMV epilogue
  k_spmm<true ><<<((size_t)N * 8 + 255) / 256, 256, 0, stream>>>((const uint4*)G8, rowptr, colv, dinv, b2, W3, nullptr, tvec, N);
  // layer 3 aggregation + residual
  k_final3<<<((size_t)N * 16 + 255) / 256, 256, 0, stream>>>(tvec, rowptr, colv, dinv, b3, x, out, N);
}

// Round 10
// 155.330 us; speedup vs baseline: 1.5374x; 1.0791x over previous
//
#include <hip/hip_runtime.h>
#include <hip/hip_bf16.h>

typedef __attribute__((ext_vector_type(8))) short short8;
typedef __attribute__((ext_vector_type(8))) __bf16 bf16x8;
typedef __attribute__((ext_vector_type(4))) float f32x4;

static __device__ __forceinline__ float bflo(unsigned u){ return __uint_as_float(u << 16); }
static __device__ __forceinline__ float bfhi(unsigned u){ return __uint_as_float(u & 0xffff0000u); }
static __device__ __forceinline__ unsigned short f2bf(float f){
  unsigned u = __float_as_uint(f);
  unsigned r = u + 0x7fffu + ((u >> 16) & 1u);
  return (unsigned short)(r >> 16);
}

// ---- fp8 e4m3 conversions ----
#if __has_builtin(__builtin_amdgcn_cvt_pk_fp8_f32)
static __device__ __forceinline__ unsigned char f2e4m3(float f){
  return (unsigned char)(__builtin_amdgcn_cvt_pk_fp8_f32(f, 0.f, 0, false) & 0xff);
}
#else
static __device__ __forceinline__ unsigned char f2e4m3(float f){
  unsigned s = (__float_as_uint(f) >> 31) << 7;
  float a = fabsf(f);
  if (a >= 448.f) return (unsigned char)(s | 0x7e);
  if (a < 0.0009765625f) return (unsigned char)s;
  if (a >= 0.015625f){
    int e; float m = frexpf(a, &e);
    int q = (int)rintf(m * 16.f);
    int E = e - 1 + 7;
    if (q == 16){ q = 8; E++; }
    if (E >= 16) return (unsigned char)(s | 0x7e);
    return (unsigned char)(s | (E << 3) | (q - 8));
  } else {
    int q = (int)rintf(a * 512.f);
    if (q > 7) return (unsigned char)(s | 0x08);
    return (unsigned char)(s | q);
  }
}
#endif

#if __has_builtin(__builtin_amdgcn_cvt_pk_f32_fp8)
static __device__ __forceinline__ float4 e4m3x4_to_f32(unsigned u){
  auto lo = __builtin_amdgcn_cvt_pk_f32_fp8((int)u, false);
  auto hi = __builtin_amdgcn_cvt_pk_f32_fp8((int)u, true);
  return make_float4(lo[0], lo[1], hi[0], hi[1]);
}
#else
static __device__ __forceinline__ float e4m3_1(unsigned b){
  unsigned s = b >> 7, e = (b >> 3) & 15, m = b & 7;
  float v = e ? ldexpf((float)(8 + m) * 0.125f, (int)e - 7) : ldexpf((float)m * 0.125f, -6);
  return s ? -v : v;
}
static __device__ __forceinline__ float4 e4m3x4_to_f32(unsigned u){
  return make_float4(e4m3_1(u & 255), e4m3_1((u >> 8) & 255), e4m3_1((u >> 16) & 255), e4m3_1(u >> 24));
}
#endif

static __device__ __forceinline__ void add8(float* acc, uint2 u){
  float4 a = e4m3x4_to_f32(u.x), b = e4m3x4_to_f32(u.y);
  acc[0] += a.x; acc[1] += a.y; acc[2] += a.z; acc[3] += a.w;
  acc[4] += b.x; acc[5] += b.y; acc[6] += b.z; acc[7] += b.w;
}

#define NBMAX  1024
#define PART_C 4096
#define STCAP  4096
#define BCAP   6144   // per-bucket ebuf capacity (mean 2046, +90 sigma)

// ---------------- bucket pipeline (no pre-count pass) ----------------

__global__ __launch_bounds__(1024) void k_part(const int* __restrict__ src, const int* __restrict__ dst,
    int* __restrict__ bpos, unsigned* __restrict__ ebuf, int E, int NB)
{
  __shared__ int hist[NBMAX + 1];
  __shared__ int hist2[NBMAX];
  __shared__ int gbase[NBMAX];
  __shared__ int sc[1024];
  __shared__ unsigned staged[PART_C];

  const int t = threadIdx.x;
  const int base = blockIdx.x * PART_C;

  for (int i = t; i < NBMAX; i += 1024){ hist[i] = 0; hist2[i] = 0; }
  __syncthreads();

  unsigned up[4];
  int bb[4];
  #pragma unroll
  for (int j = 0; j < 4; j++){
    int e = base + j * 1024 + t;
    if (e < E){
      int s = src[e], d = dst[e];
      bb[j] = d >> 7;
      up[j] = ((unsigned)s << 7) | (unsigned)(d & 127);
      atomicAdd(&hist[bb[j]], 1);
    } else bb[j] = -1;
  }
  __syncthreads();

  int v = (t < NB) ? hist[t] : 0;
  sc[t] = v; __syncthreads();
  for (int off = 1; off < 1024; off <<= 1){
    int u = (t >= off) ? sc[t - off] : 0;
    __syncthreads();
    sc[t] += u;
    __syncthreads();
  }
  int incl = sc[t];
  if (t < NB) hist[t] = incl - v;
  if (t == NB - 1) hist[NB] = incl;
  if (t < NB && v > 0) gbase[t] = t * BCAP + atomicAdd(&bpos[t], v);
  __syncthreads();

  #pragma unroll
  for (int j = 0; j < 4; j++){
    if (bb[j] >= 0){
      int r = atomicAdd(&hist2[bb[j]], 1);
      staged[hist[bb[j]] + r] = up[j];
    }
  }
  __syncthreads();

  int total = hist[NB];
  for (int i = t; i < total; i += 1024){
    int lo = 0, hi = NB;
    while (hi - lo > 1){
      int mid = (lo + hi) >> 1;
      if (hist[mid] <= i) lo = mid; else hi = mid;
    }
    ebuf[gbase[lo] + (i - hist[lo])] = staged[i];
  }
}

__global__ __launch_bounds__(1024) void k_cscan(const int* __restrict__ cnts, int* __restrict__ bstart,
    int* __restrict__ rowptr, int NB, int N, int E){
  __shared__ int sc[1024];
  const int t = threadIdx.x;
  int v = (t < NB) ? cnts[t] : 0;
  sc[t] = v; __syncthreads();
  for (int off = 1; off < 1024; off <<= 1){
    int u = (t >= off) ? sc[t - off] : 0;
    __syncthreads();
    sc[t] += u;
    __syncthreads();
  }
  if (t < NB) bstart[t] = sc[t] - v;
  if (t == 0){ bstart[NB] = E; rowptr[N] = E; }
}

__global__ __launch_bounds__(256) void k_bsort(const unsigned* __restrict__ ebuf, const int* __restrict__ cnts,
    const int* __restrict__ bstart, int* __restrict__ rowptr, int* __restrict__ colv,
    float* __restrict__ dinv, int n)
{
  __shared__ int cl[128];
  __shared__ int sc2[256];
  __shared__ unsigned stg[STCAP];

  const int t = threadIdx.x;
  const int b = blockIdx.x;
  const int r0 = b << 7;
  const int rbeg = b * BCAP;
  const int total = cnts[b];
  const int wbeg = bstart[b];

  if (t < 128) cl[t] = 0;
  __syncthreads();
  for (int i = t; i < total; i += 256) atomicAdd(&cl[ebuf[rbeg + i] & 127u], 1);
  __syncthreads();

  int v = (t < 128) ? cl[t] : 0;
  sc2[t] = v; __syncthreads();
  for (int off = 1; off < 256; off <<= 1){
    int u = (t >= off) ? sc2[t - off] : 0;
    __syncthreads();
    sc2[t] += u;
    __syncthreads();
  }
  int excl = sc2[t] - v;
  if (t < 128){
    int node = r0 + t;
    if (node < n){
      rowptr[node] = wbeg + excl;
      dinv[node]   = rsqrtf((float)(v + 1));
    }
    cl[t] = excl;
  }
  __syncthreads();

  if (total <= STCAP){
    for (int i = t; i < total; i += 256){
      unsigned u = ebuf[rbeg + i];
      int p = atomicAdd(&cl[u & 127u], 1);
      stg[p] = u >> 7;
    }
    __syncthreads();
    for (int i = t; i < total; i += 256) colv[wbeg + i] = (int)stg[i];
  } else {
    for (int i = t; i < total; i += 256){
      unsigned u = ebuf[rbeg + i];
      int p = atomicAdd(&cl[u & 127u], 1);
      colv[wbeg + p] = (int)(u >> 7);
    }
  }
}

// ---------------- MFMA GEMM: G8[i,:] = fp8( dinv[i] * (A[i,:] @ W) ) ----------------

template<bool AF32>
__global__ __launch_bounds__(512) void k_gemm_mfma(const void* __restrict__ Ain, const float* __restrict__ W,
    const float* __restrict__ dinv, unsigned char* __restrict__ G8, int n)
{
  __shared__ unsigned short At[128 * 136];
  __shared__ float dl[128];

  const int t = threadIdx.x;
  const int rowBase = blockIdx.x * 128;
  const int w  = t >> 6;
  const int l  = t & 63;
  const int ln = l & 15;
  const int lg = l >> 4;

  if (t < 128){
    int gr = rowBase + t;
    dl[t] = (gr < n) ? dinv[gr] : 0.f;
  }

  #pragma unroll
  for (int i = 0; i < 4; i++){
    int flat = i * 4096 + t * 8;
    int r = flat >> 7, c = flat & 127;
    int gr = rowBase + r;
    unsigned short tmp[8];
    if constexpr (AF32){
      const float* A = (const float*)Ain;
      float4 v0 = make_float4(0.f,0.f,0.f,0.f), v1 = v0;
      if (gr < n){
        v0 = *(const float4*)(A + (size_t)gr * 128 + c);
        v1 = *(const float4*)(A + (size_t)gr * 128 + c + 4);
      }
      tmp[0]=f2bf(v0.x); tmp[1]=f2bf(v0.y); tmp[2]=f2bf(v0.z); tmp[3]=f2bf(v0.w);
      tmp[4]=f2bf(v1.x); tmp[5]=f2bf(v1.y); tmp[6]=f2bf(v1.z); tmp[7]=f2bf(v1.w);
    } else {
      const unsigned short* A = (const unsigned short*)Ain;
      short8 v = {};
      if (gr < n) v = *(const short8*)(A + (size_t)gr * 128 + c);
      *(short8*)tmp = v;
    }
    int g = (c >> 3) ^ (r & 7);
    *(short8*)((char*)At + r * 256 + g * 16) = *(const short8*)tmp;
  }

  bf16x8 bfr[4];
  #pragma unroll
  for (int kk = 0; kk < 4; kk++){
    short8 tmp;
    #pragma unroll
    for (int j = 0; j < 8; j++){
      float wv = W[(kk * 32 + lg * 8 + j) * 128 + (w * 16 + ln)];
      tmp[j] = (short)f2bf(wv);
    }
    bfr[kk] = __builtin_bit_cast(bf16x8, tmp);
  }

  f32x4 acc[8];
  #pragma unroll
  for (int m = 0; m < 8; m++) acc[m] = (f32x4){0.f,0.f,0.f,0.f};

  __syncthreads();

  #pragma unroll
  for (int m = 0; m < 8; m++){
    int row = m * 16 + ln;
    #pragma unroll
    for (int kk = 0; kk < 4; kk++){
      int g = (kk * 4 + lg) ^ (row & 7);
      short8 av = *(const short8*)((const char*)At + row * 256 + g * 16);
      acc[m] = __builtin_amdgcn_mfma_f32_16x16x32_bf16(
          __builtin_bit_cast(bf16x8, av), bfr[kk], acc[m], 0, 0, 0);
    }
  }

  __syncthreads();
  unsigned char* At8 = (unsigned char*)At;

  #pragma unroll
  for (int m = 0; m < 8; m++){
    #pragma unroll
    for (int r = 0; r < 4; r++){
      int row = m * 16 + lg * 4 + r;
      At8[row * 136 + w * 16 + ln] = f2e4m3(dl[row] * acc[m][r]);
    }
  }
  __syncthreads();

  {
    int r = t >> 2, c = (t & 3) * 32;
    int gr = rowBase + r;
    if (gr < n){
      uint4 a = *(const uint4*)(At8 + r * 136 + c);
      uint4 b = *(const uint4*)(At8 + r * 136 + c + 16);
      *(uint4*)(G8 + (size_t)gr * 128 + c)      = a;
      *(uint4*)(G8 + (size_t)gr * 128 + c + 16) = b;
    }
  }
}

// ---------------- SpMM: 16 lanes/row, uint2 (8 fp8) per lane; unroll 8/4/1 ----------------
// LAST=false: H(bf16) = relu(dinv*agg + b)
// LAST=true : tvec[row] = dinv * dot(relu(dinv*agg + b), W3)   (H never materialized)

template<bool LAST>
__global__ __launch_bounds__(256) void k_spmm(const uint2* __restrict__ G8, const int* __restrict__ rowptr,
    const int* __restrict__ colv, const float* __restrict__ dinv, const float* __restrict__ bias,
    const float* __restrict__ W3, unsigned* __restrict__ H, float* __restrict__ tvec, int n)
{
  int tid = blockIdx.x * 256 + threadIdx.x;
  int row = tid >> 4;
  int gl  = tid & 15;
  if (row >= n) return;

  float acc[8] = {0,0,0,0,0,0,0,0};
  add8(acc, G8[(size_t)row * 16 + gl]);         // self loop
  int e = rowptr[row], e1 = rowptr[row + 1];

  for (; e + 8 <= e1; e += 8){
    int s0 = colv[e    ], s1 = colv[e + 1], s2 = colv[e + 2], s3 = colv[e + 3];
    int s4 = colv[e + 4], s5 = colv[e + 5], s6 = colv[e + 6], s7 = colv[e + 7];
    uint2 v0 = G8[(size_t)s0 * 16 + gl];
    uint2 v1 = G8[(size_t)s1 * 16 + gl];
    uint2 v2 = G8[(size_t)s2 * 16 + gl];
    uint2 v3 = G8[(size_t)s3 * 16 + gl];
    uint2 v4 = G8[(size_t)s4 * 16 + gl];
    uint2 v5 = G8[(size_t)s5 * 16 + gl];
    uint2 v6 = G8[(size_t)s6 * 16 + gl];
    uint2 v7 = G8[(size_t)s7 * 16 + gl];
    add8(acc, v0); add8(acc, v1); add8(acc, v2); add8(acc, v3);
    add8(acc, v4); add8(acc, v5); add8(acc, v6); add8(acc, v7);
  }
  for (; e + 4 <= e1; e += 4){
    int s0 = colv[e], s1 = colv[e + 1], s2 = colv[e + 2], s3 = colv[e + 3];
    uint2 v0 = G8[(size_t)s0 * 16 + gl];
    uint2 v1 = G8[(size_t)s1 * 16 + gl];
    uint2 v2 = G8[(size_t)s2 * 16 + gl];
    uint2 v3 = G8[(size_t)s3 * 16 + gl];
    add8(acc, v0); add8(acc, v1); add8(acc, v2); add8(acc, v3);
  }
  for (; e < e1; ++e) add8(acc, G8[(size_t)colv[e] * 16 + gl]);

  float dv = dinv[row];
  float r[8];
  {
    float4 b0 = *(const float4*)(bias + gl * 8);
    float4 b1 = *(const float4*)(bias + gl * 8 + 4);
    r[0] = fmaxf(fmaf(dv, acc[0], b0.x), 0.f);
    r[1] = fmaxf(fmaf(dv, acc[1], b0.y), 0.f);
    r[2] = fmaxf(fmaf(dv, acc[2], b0.z), 0.f);
    r[3] = fmaxf(fmaf(dv, acc[3], b0.w), 0.f);
    r[4] = fmaxf(fmaf(dv, acc[4], b1.x), 0.f);
    r[5] = fmaxf(fmaf(dv, acc[5], b1.y), 0.f);
    r[6] = fmaxf(fmaf(dv, acc[6], b1.z), 0.f);
    r[7] = fmaxf(fmaf(dv, acc[7], b1.w), 0.f);
  }

  if constexpr (!LAST){
    uint4 o;
    o.x = (unsigned)f2bf(r[0]) | ((unsigned)f2bf(r[1]) << 16);
    o.y = (unsigned)f2bf(r[2]) | ((unsigned)f2bf(r[3]) << 16);
    o.z = (unsigned)f2bf(r[4]) | ((unsigned)f2bf(r[5]) << 16);
    o.w = (unsigned)f2bf(r[6]) | ((unsigned)f2bf(r[7]) << 16);
    *(uint4*)(H + (size_t)row * 64 + gl * 4) = o;
  } else {
    float4 w0 = *(const float4*)(W3 + gl * 8);
    float4 w1 = *(const float4*)(W3 + gl * 8 + 4);
    float s = r[0]*w0.x + r[1]*w0.y + r[2]*w0.z + r[3]*w0.w
            + r[4]*w1.x + r[5]*w1.y + r[6]*w1.z + r[7]*w1.w;
    s += __shfl_xor(s, 1); s += __shfl_xor(s, 2);
    s += __shfl_xor(s, 4); s += __shfl_xor(s, 8);
    if (gl == 0) tvec[row] = dv * s;
  }
}

// ---------------- layer 3 final ----------------

__global__ __launch_bounds__(256) void k_final3(const float* __restrict__ tvec, const int* __restrict__ rowptr,
    const int* __restrict__ colv, const float* __restrict__ dinv, const float* __restrict__ b3,
    const float* __restrict__ x, float* __restrict__ out, int n)
{
  int tid = blockIdx.x * 256 + threadIdx.x;
  int row = tid >> 4;
  int gl  = tid & 15;
  if (row >= n) return;
  float s = 0.f;
  int e0 = rowptr[row], e1 = rowptr[row + 1];
  for (int e = e0 + gl; e < e1; e += 16) s += tvec[colv[e]];
  s += __shfl_xor(s, 1); s += __shfl_xor(s, 2);
  s += __shfl_xor(s, 4); s += __shfl_xor(s, 8);
  if (gl == 0){
    s += tvec[row];
    float v = fmaxf(fmaf(dinv[row], s, b3[0]), 0.f);
    out[row] = v + x[(size_t)row * 128 + 127];
  }
}

// ---------------- launch ----------------

extern "C" void kernel_launch(void* const* d_in, const int* in_sizes, int n_in,
                              void* d_out, int out_size, void* d_ws, size_t ws_size,
                              hipStream_t stream)
{
  const float* x  = (const float*)d_in[0];
  const int*   ei = (const int*)d_in[1];
  const float* W1 = (const float*)d_in[3];
  const float* b1 = (const float*)d_in[4];
  const float* W2 = (const float*)d_in[5];
  const float* b2 = (const float*)d_in[6];
  const float* W3 = (const float*)d_in[7];
  const float* b3 = (const float*)d_in[8];
  float* out = (float*)d_out;

  const int N = in_sizes[0] / 128;
  const int E = in_sizes[1] / 2;
  const int* src = ei;
  const int* dst = ei + E;
  const int NB = (N + 127) >> 7;

  char* wsb = (char*)d_ws;
  size_t off = 0;
  auto carve = [&](size_t bytes) -> void* {
    void* p = wsb + off;
    off += bytes;
    off = (off + 255) & ~(size_t)255;
    return p;
  };
  float*    dinv   = (float*)carve((size_t)N * 4);
  int*      rowptr = (int*)carve((size_t)(N + 1) * 4);
  int*      colv   = (int*)carve((size_t)E * 4);
  int*      bstart = (int*)carve((size_t)(NB + 1) * 4);
  int*      bpos   = (int*)carve((size_t)NB * 4);
  float*    tvec   = (float*)carve((size_t)N * 4);
  unsigned char* G8 = (unsigned char*)carve((size_t)N * 128);  // fp8 N x 128
  unsigned* H      = (unsigned*)carve((size_t)N * 256);        // bf16 N x 128 (layer1 only)
  unsigned* ebuf   = (unsigned*)H;                             // overlay: NB*BCAP*4 <= N*256

  hipMemsetAsync(bpos, 0, (size_t)NB * 4, stream);
  k_part  <<<(E + PART_C - 1) / PART_C, 1024, 0, stream>>>(src, dst, bpos, ebuf, E, NB);
  k_cscan <<<1, 1024, 0, stream>>>(bpos, bstart, rowptr, NB, N, E);
  k_bsort <<<NB, 256, 0, stream>>>(ebuf, bpos, bstart, rowptr, colv, dinv, N);

  // layer 1
  k_gemm_mfma<true ><<<(N + 127) / 128, 512, 0, stream>>>(x, W1, dinv, G8, N);
  k_spmm<false><<<((size_t)N * 16 + 255) / 256, 256, 0, stream>>>((const uint2*)G8, rowptr, colv, dinv, b1, nullptr, H, nullptr, N);
  // layer 2
  k_gemm_mfma<false><<<(N + 127) / 128, 512, 0, stream>>>(H, W2, dinv, G8, N);
  // layer 2 aggregation fused with layer-3 GEMV epilogue
  k_spmm<true ><<<((size_t)N * 16 + 255) / 256, 256, 0, stream>>>((const uint2*)G8, rowptr, colv, dinv, b2, W3, nullptr, tvec, N);
  // layer 3 aggregation + residual
  k_final3<<<((size_t)N * 16 + 255) / 256, 256, 0, stream>>>(tvec, rowptr, colv, dinv, b3, x, out, N);
}

// Round 12
// 152.454 us; speedup vs baseline: 1.5664x; 1.0189x over previous
//
#include <hip/hip_runtime.h>
#include <hip/hip_bf16.h>

typedef __attribute__((ext_vector_type(8))) short short8;
typedef __attribute__((ext_vector_type(8))) __bf16 bf16x8;
typedef __attribute__((ext_vector_type(4))) float f32x4;

static __device__ __forceinline__ float bflo(unsigned u){ return __uint_as_float(u << 16); }
static __device__ __forceinline__ float bfhi(unsigned u){ return __uint_as_float(u & 0xffff0000u); }
static __device__ __forceinline__ unsigned short f2bf(float f){
  unsigned u = __float_as_uint(f);
  unsigned r = u + 0x7fffu + ((u >> 16) & 1u);
  return (unsigned short)(r >> 16);
}

// ---- fp8 e4m3 conversions ----
#if __has_builtin(__builtin_amdgcn_cvt_pk_fp8_f32)
static __device__ __forceinline__ unsigned char f2e4m3(float f){
  return (unsigned char)(__builtin_amdgcn_cvt_pk_fp8_f32(f, 0.f, 0, false) & 0xff);
}
#else
static __device__ __forceinline__ unsigned char f2e4m3(float f){
  unsigned s = (__float_as_uint(f) >> 31) << 7;
  float a = fabsf(f);
  if (a >= 448.f) return (unsigned char)(s | 0x7e);
  if (a < 0.0009765625f) return (unsigned char)s;
  if (a >= 0.015625f){
    int e; float m = frexpf(a, &e);
    int q = (int)rintf(m * 16.f);
    int E = e - 1 + 7;
    if (q == 16){ q = 8; E++; }
    if (E >= 16) return (unsigned char)(s | 0x7e);
    return (unsigned char)(s | (E << 3) | (q - 8));
  } else {
    int q = (int)rintf(a * 512.f);
    if (q > 7) return (unsigned char)(s | 0x08);
    return (unsigned char)(s | q);
  }
}
#endif

#if __has_builtin(__builtin_amdgcn_cvt_pk_f32_fp8)
static __device__ __forceinline__ float4 e4m3x4_to_f32(unsigned u){
  auto lo = __builtin_amdgcn_cvt_pk_f32_fp8((int)u, false);
  auto hi = __builtin_amdgcn_cvt_pk_f32_fp8((int)u, true);
  return make_float4(lo[0], lo[1], hi[0], hi[1]);
}
#else
static __device__ __forceinline__ float e4m3_1(unsigned b){
  unsigned s = b >> 7, e = (b >> 3) & 15, m = b & 7;
  float v = e ? ldexpf((float)(8 + m) * 0.125f, (int)e - 7) : ldexpf((float)m * 0.125f, -6);
  return s ? -v : v;
}
static __device__ __forceinline__ float4 e4m3x4_to_f32(unsigned u){
  return make_float4(e4m3_1(u & 255), e4m3_1((u >> 8) & 255), e4m3_1((u >> 16) & 255), e4m3_1(u >> 24));
}
#endif

static __device__ __forceinline__ void add8(float* acc, uint2 u){
  float4 a = e4m3x4_to_f32(u.x), b = e4m3x4_to_f32(u.y);
  acc[0] += a.x; acc[1] += a.y; acc[2] += a.z; acc[3] += a.w;
  acc[4] += b.x; acc[5] += b.y; acc[6] += b.z; acc[7] += b.w;
}

#define NBMAX  1024
#define PART_C 4096
#define STCAP  4096
#define BCAP   6144   // per-bucket ebuf capacity (mean 2046, +90 sigma)

// ---------------- bucket pipeline (no pre-count pass) ----------------

__global__ __launch_bounds__(1024) void k_part(const int* __restrict__ src, const int* __restrict__ dst,
    int* __restrict__ bpos, unsigned* __restrict__ ebuf, int E, int NB)
{
  __shared__ int hist[NBMAX + 1];
  __shared__ int hist2[NBMAX];
  __shared__ int gbase[NBMAX];
  __shared__ int sc[1024];
  __shared__ unsigned staged[PART_C];
  __shared__ unsigned short sbkt[PART_C];

  const int t = threadIdx.x;
  const int base = blockIdx.x * PART_C;

  for (int i = t; i < NBMAX; i += 1024){ hist[i] = 0; hist2[i] = 0; }
  __syncthreads();

  unsigned up[4];
  int bb[4];
  #pragma unroll
  for (int j = 0; j < 4; j++){
    int e = base + j * 1024 + t;
    if (e < E){
      int s = src[e], d = dst[e];
      bb[j] = d >> 7;
      up[j] = ((unsigned)s << 7) | (unsigned)(d & 127);
      atomicAdd(&hist[bb[j]], 1);
    } else bb[j] = -1;
  }
  __syncthreads();

  int v = (t < NB) ? hist[t] : 0;
  sc[t] = v; __syncthreads();
  for (int off = 1; off < 1024; off <<= 1){
    int u = (t >= off) ? sc[t - off] : 0;
    __syncthreads();
    sc[t] += u;
    __syncthreads();
  }
  int incl = sc[t];
  if (t < NB) hist[t] = incl - v;
  if (t == NB - 1) hist[NB] = incl;
  if (t < NB && v > 0) gbase[t] = t * BCAP + atomicAdd(&bpos[t], v);
  __syncthreads();

  #pragma unroll
  for (int j = 0; j < 4; j++){
    if (bb[j] >= 0){
      int r = atomicAdd(&hist2[bb[j]], 1);
      int p = hist[bb[j]] + r;
      staged[p] = up[j];
      sbkt[p] = (unsigned short)bb[j];
    }
  }
  __syncthreads();

  int total = hist[NB];
  for (int i = t; i < total; i += 1024){
    int b = sbkt[i];
    ebuf[gbase[b] + (i - hist[b])] = staged[i];
  }
}

__global__ __launch_bounds__(1024) void k_cscan(const int* __restrict__ cnts, int* __restrict__ bstart,
    int* __restrict__ rowptr, int NB, int N, int E){
  __shared__ int sc[1024];
  const int t = threadIdx.x;
  int v = (t < NB) ? cnts[t] : 0;
  sc[t] = v; __syncthreads();
  for (int off = 1; off < 1024; off <<= 1){
    int u = (t >= off) ? sc[t - off] : 0;
    __syncthreads();
    sc[t] += u;
    __syncthreads();
  }
  if (t < NB) bstart[t] = sc[t] - v;
  if (t == 0){ bstart[NB] = E; rowptr[N] = E; }
}

__global__ __launch_bounds__(256) void k_bsort(const unsigned* __restrict__ ebuf, const int* __restrict__ cnts,
    const int* __restrict__ bstart, int* __restrict__ rowptr, int* __restrict__ colv,
    float* __restrict__ dinv, int n)
{
  __shared__ int cl[128];
  __shared__ int sc2[256];
  __shared__ unsigned stg[STCAP];

  const int t = threadIdx.x;
  const int b = blockIdx.x;
  const int r0 = b << 7;
  const int rbeg = b * BCAP;
  const int total = cnts[b];
  const int wbeg = bstart[b];

  if (t < 128) cl[t] = 0;
  __syncthreads();
  for (int i = t; i < total; i += 256) atomicAdd(&cl[ebuf[rbeg + i] & 127u], 1);
  __syncthreads();

  int v = (t < 128) ? cl[t] : 0;
  sc2[t] = v; __syncthreads();
  for (int off = 1; off < 256; off <<= 1){
    int u = (t >= off) ? sc2[t - off] : 0;
    __syncthreads();
    sc2[t] += u;
    __syncthreads();
  }
  int excl = sc2[t] - v;
  if (t < 128){
    int node = r0 + t;
    if (node < n){
      rowptr[node] = wbeg + excl;
      dinv[node]   = rsqrtf((float)(v + 1));
    }
    cl[t] = excl;
  }
  __syncthreads();

  if (total <= STCAP){
    for (int i = t; i < total; i += 256){
      unsigned u = ebuf[rbeg + i];
      int p = atomicAdd(&cl[u & 127u], 1);
      stg[p] = u >> 7;
    }
    __syncthreads();
    for (int i = t; i < total; i += 256) colv[wbeg + i] = (int)stg[i];
  } else {
    for (int i = t; i < total; i += 256){
      unsigned u = ebuf[rbeg + i];
      int p = atomicAdd(&cl[u & 127u], 1);
      colv[wbeg + p] = (int)(u >> 7);
    }
  }
}

// ---------------- MFMA GEMM: G8[i,:] = fp8( dinv[i] * (A[i,:] @ W) ) ----------------

template<bool AF32>
__global__ __launch_bounds__(512) void k_gemm_mfma(const void* __restrict__ Ain, const float* __restrict__ W,
    const float* __restrict__ dinv, unsigned char* __restrict__ G8, int n)
{
  __shared__ unsigned short At[128 * 136];
  __shared__ float dl[128];

  const int t = threadIdx.x;
  const int rowBase = blockIdx.x * 128;
  const int w  = t >> 6;
  const int l  = t & 63;
  const int ln = l & 15;
  const int lg = l >> 4;

  if (t < 128){
    int gr = rowBase + t;
    dl[t] = (gr < n) ? dinv[gr] : 0.f;
  }

  #pragma unroll
  for (int i = 0; i < 4; i++){
    int flat = i * 4096 + t * 8;
    int r = flat >> 7, c = flat & 127;
    int gr = rowBase + r;
    unsigned short tmp[8];
    if constexpr (AF32){
      const float* A = (const float*)Ain;
      float4 v0 = make_float4(0.f,0.f,0.f,0.f), v1 = v0;
      if (gr < n){
        v0 = *(const float4*)(A + (size_t)gr * 128 + c);
        v1 = *(const float4*)(A + (size_t)gr * 128 + c + 4);
      }
      tmp[0]=f2bf(v0.x); tmp[1]=f2bf(v0.y); tmp[2]=f2bf(v0.z); tmp[3]=f2bf(v0.w);
      tmp[4]=f2bf(v1.x); tmp[5]=f2bf(v1.y); tmp[6]=f2bf(v1.z); tmp[7]=f2bf(v1.w);
    } else {
      const unsigned short* A = (const unsigned short*)Ain;
      short8 v = {};
      if (gr < n) v = *(const short8*)(A + (size_t)gr * 128 + c);
      *(short8*)tmp = v;
    }
    int g = (c >> 3) ^ (r & 7);
    *(short8*)((char*)At + r * 256 + g * 16) = *(const short8*)tmp;
  }

  bf16x8 bfr[4];
  #pragma unroll
  for (int kk = 0; kk < 4; kk++){
    short8 tmp;
    #pragma unroll
    for (int j = 0; j < 8; j++){
      float wv = W[(kk * 32 + lg * 8 + j) * 128 + (w * 16 + ln)];
      tmp[j] = (short)f2bf(wv);
    }
    bfr[kk] = __builtin_bit_cast(bf16x8, tmp);
  }

  f32x4 acc[8];
  #pragma unroll
  for (int m = 0; m < 8; m++) acc[m] = (f32x4){0.f,0.f,0.f,0.f};

  __syncthreads();

  #pragma unroll
  for (int m = 0; m < 8; m++){
    int row = m * 16 + ln;
    #pragma unroll
    for (int kk = 0; kk < 4; kk++){
      int g = (kk * 4 + lg) ^ (row & 7);
      short8 av = *(const short8*)((const char*)At + row * 256 + g * 16);
      acc[m] = __builtin_amdgcn_mfma_f32_16x16x32_bf16(
          __builtin_bit_cast(bf16x8, av), bfr[kk], acc[m], 0, 0, 0);
    }
  }

  __syncthreads();
  unsigned char* At8 = (unsigned char*)At;

  #pragma unroll
  for (int m = 0; m < 8; m++){
    #pragma unroll
    for (int r = 0; r < 4; r++){
      int row = m * 16 + lg * 4 + r;
      At8[row * 136 + w * 16 + ln] = f2e4m3(dl[row] * acc[m][r]);
    }
  }
  __syncthreads();

  {
    int r = t >> 2, c = (t & 3) * 32;
    int gr = rowBase + r;
    if (gr < n){
      uint4 a = *(const uint4*)(At8 + r * 136 + c);
      uint4 b = *(const uint4*)(At8 + r * 136 + c + 16);
      *(uint4*)(G8 + (size_t)gr * 128 + c)      = a;
      *(uint4*)(G8 + (size_t)gr * 128 + c + 16) = b;
    }
  }
}

// ---------------- SpMM: 16 lanes/row, uint2 (8 fp8) per lane; unroll 8/4/1 ----------------
// LAST=false: H(bf16) = relu(dinv*agg + b)
// LAST=true : tvec[row] = dinv * dot(relu(dinv*agg + b), W3)   (H never materialized)

template<bool LAST>
__global__ __launch_bounds__(256) void k_spmm(const uint2* __restrict__ G8, const int* __restrict__ rowptr,
    const int* __restrict__ colv, const float* __restrict__ dinv, const float* __restrict__ bias,
    const float* __restrict__ W3, unsigned* __restrict__ H, float* __restrict__ tvec, int n)
{
  int tid = blockIdx.x * 256 + threadIdx.x;
  int row = tid >> 4;
  int gl  = tid & 15;
  if (row >= n) return;

  float acc[8] = {0,0,0,0,0,0,0,0};
  add8(acc, G8[(size_t)row * 16 + gl]);         // self loop
  int e = rowptr[row], e1 = rowptr[row + 1];

  for (; e + 8 <= e1; e += 8){
    int s0 = colv[e    ], s1 = colv[e + 1], s2 = colv[e + 2], s3 = colv[e + 3];
    int s4 = colv[e + 4], s5 = colv[e + 5], s6 = colv[e + 6], s7 = colv[e + 7];
    uint2 v0 = G8[(size_t)s0 * 16 + gl];
    uint2 v1 = G8[(size_t)s1 * 16 + gl];
    uint2 v2 = G8[(size_t)s2 * 16 + gl];
    uint2 v3 = G8[(size_t)s3 * 16 + gl];
    uint2 v4 = G8[(size_t)s4 * 16 + gl];
    uint2 v5 = G8[(size_t)s5 * 16 + gl];
    uint2 v6 = G8[(size_t)s6 * 16 + gl];
    uint2 v7 = G8[(size_t)s7 * 16 + gl];
    add8(acc, v0); add8(acc, v1); add8(acc, v2); add8(acc, v3);
    add8(acc, v4); add8(acc, v5); add8(acc, v6); add8(acc, v7);
  }
  for (; e + 4 <= e1; e += 4){
    int s0 = colv[e], s1 = colv[e + 1], s2 = colv[e + 2], s3 = colv[e + 3];
    uint2 v0 = G8[(size_t)s0 * 16 + gl];
    uint2 v1 = G8[(size_t)s1 * 16 + gl];
    uint2 v2 = G8[(size_t)s2 * 16 + gl];
    uint2 v3 = G8[(size_t)s3 * 16 + gl];
    add8(acc, v0); add8(acc, v1); add8(acc, v2); add8(acc, v3);
  }
  for (; e < e1; ++e) add8(acc, G8[(size_t)colv[e] * 16 + gl]);

  float dv = dinv[row];
  float r[8];
  {
    float4 b0 = *(const float4*)(bias + gl * 8);
    float4 b1 = *(const float4*)(bias + gl * 8 + 4);
    r[0] = fmaxf(fmaf(dv, acc[0], b0.x), 0.f);
    r[1] = fmaxf(fmaf(dv, acc[1], b0.y), 0.f);
    r[2] = fmaxf(fmaf(dv, acc[2], b0.z), 0.f);
    r[3] = fmaxf(fmaf(dv, acc[3], b0.w), 0.f);
    r[4] = fmaxf(fmaf(dv, acc[4], b1.x), 0.f);
    r[5] = fmaxf(fmaf(dv, acc[5], b1.y), 0.f);
    r[6] = fmaxf(fmaf(dv, acc[6], b1.z), 0.f);
    r[7] = fmaxf(fmaf(dv, acc[7], b1.w), 0.f);
  }

  if constexpr (!LAST){
    uint4 o;
    o.x = (unsigned)f2bf(r[0]) | ((unsigned)f2bf(r[1]) << 16);
    o.y = (unsigned)f2bf(r[2]) | ((unsigned)f2bf(r[3]) << 16);
    o.z = (unsigned)f2bf(r[4]) | ((unsigned)f2bf(r[5]) << 16);
    o.w = (unsigned)f2bf(r[6]) | ((unsigned)f2bf(r[7]) << 16);
    *(uint4*)(H + (size_t)row * 64 + gl * 4) = o;
  } else {
    float4 w0 = *(const float4*)(W3 + gl * 8);
    float4 w1 = *(const float4*)(W3 + gl * 8 + 4);
    float s = r[0]*w0.x + r[1]*w0.y + r[2]*w0.z + r[3]*w0.w
            + r[4]*w1.x + r[5]*w1.y + r[6]*w1.z + r[7]*w1.w;
    s += __shfl_xor(s, 1); s += __shfl_xor(s, 2);
    s += __shfl_xor(s, 4); s += __shfl_xor(s, 8);
    if (gl == 0) tvec[row] = dv * s;
  }
}

// ---------------- layer 3 final ----------------

__global__ __launch_bounds__(256) void k_final3(const float* __restrict__ tvec, const int* __restrict__ rowptr,
    const int* __restrict__ colv, const float* __restrict__ dinv, const float* __restrict__ b3,
    const float* __restrict__ x, float* __restrict__ out, int n)
{
  int tid = blockIdx.x * 256 + threadIdx.x;
  int row = tid >> 4;
  int gl  = tid & 15;
  if (row >= n) return;
  float s = 0.f;
  int e0 = rowptr[row], e1 = rowptr[row + 1];
  for (int e = e0 + gl; e < e1; e += 16) s += tvec[colv[e]];
  s += __shfl_xor(s, 1); s += __shfl_xor(s, 2);
  s += __shfl_xor(s, 4); s += __shfl_xor(s, 8);
  if (gl == 0){
    s += tvec[row];
    float v = fmaxf(fmaf(dinv[row], s, b3[0]), 0.f);
    out[row] = v + x[(size_t)row * 128 + 127];
  }
}

// ---------------- launch ----------------

extern "C" void kernel_launch(void* const* d_in, const int* in_sizes, int n_in,
                              void* d_out, int out_size, void* d_ws, size_t ws_size,
                              hipStream_t stream)
{
  const float* x  = (const float*)d_in[0];
  const int*   ei = (const int*)d_in[1];
  const float* W1 = (const float*)d_in[3];
  const float* b1 = (const float*)d_in[4];
  const float* W2 = (const float*)d_in[5];
  const float* b2 = (const float*)d_in[6];
  const float* W3 = (const float*)d_in[7];
  const float* b3 = (const float*)d_in[8];
  float* out = (float*)d_out;

  const int N = in_sizes[0] / 128;
  const int E = in_sizes[1] / 2;
  const int* src = ei;
  const int* dst = ei + E;
  const int NB = (N + 127) >> 7;

  char* wsb = (char*)d_ws;
  size_t off = 0;
  auto carve = [&](size_t bytes) -> void* {
    void* p = wsb + off;
    off += bytes;
    off = (off + 255) & ~(size_t)255;
    return p;
  };
  float*    dinv   = (float*)carve((size_t)N * 4);
  int*      rowptr = (int*)carve((size_t)(N + 1) * 4);
  int*      colv   = (int*)carve((size_t)E * 4);
  int*      bstart = (int*)carve((size_t)(NB + 1) * 4);
  int*      bpos   = (int*)carve((size_t)NB * 4);
  float*    tvec   = (float*)carve((size_t)N * 4);
  unsigned char* G8 = (unsigned char*)carve((size_t)N * 128);  // fp8 N x 128
  unsigned* H      = (unsigned*)carve((size_t)N * 256);        // bf16 N x 128 (layer1 only)
  unsigned* ebuf   = (unsigned*)H;                             // overlay: NB*BCAP*4 <= N*256

  hipMemsetAsync(bpos, 0, (size_t)NB * 4, stream);
  k_part  <<<(E + PART_C - 1) / PART_C, 1024, 0, stream>>>(src, dst, bpos, ebuf, E, NB);
  k_cscan <<<1, 1024, 0, stream>>>(bpos, bstart, rowptr, NB, N, E);
  k_bsort <<<NB, 256, 0, stream>>>(ebuf, bpos, bstart, rowptr, colv, dinv, N);

  // layer 1
  k_gemm_mfma<true ><<<(N + 127) / 128, 512, 0, stream>>>(x, W1, dinv, G8, N);
  k_spmm<false><<<((size_t)N * 16 + 255) / 256, 256, 0, stream>>>((const uint2*)G8, rowptr, colv, dinv, b1, nullptr, H, nullptr, N);
  // layer 2
  k_gemm_mfma<false><<<(N + 127) / 128, 512, 0, stream>>>(H, W2, dinv, G8, N);
  // layer 2 aggregation fused with layer-3 GEMV epilogue
  k_spmm<true ><<<((size_t)N * 16 + 255) / 256, 256, 0, stream>>>((const uint2*)G8, rowptr, colv, dinv, b2, W3, nullptr, tvec, N);
  // layer 3 aggregation + residual
  k_final3<<<((size_t)N * 16 + 255) / 256, 256, 0, stream>>>(tvec, rowptr, colv, dinv, b3, x, out, N);
}